// Round 6
// baseline (669.968 us; speedup 1.0000x reference)
//
#include <hip/hip_runtime.h>
#include <stdint.h>

#define BB 32
#define NN 2048
#define HH 128
#define BN (BB*NN)

typedef short v8s __attribute__((ext_vector_type(8)));
typedef float v4f __attribute__((ext_vector_type(4)));

__device__ __forceinline__ unsigned short f2b(float f){
  union { float f; unsigned int i; } v; v.f = f;
  unsigned int x = v.i;
  unsigned int r = x + 0x7FFFu + ((x >> 16) & 1u);   // RNE f32 -> bf16
  return (unsigned short)(r >> 16);
}
__device__ __forceinline__ unsigned int pk2(float a, float b){
  return (unsigned int)f2b(a) | ((unsigned int)f2b(b) << 16);
}
__device__ __forceinline__ float frcp(float x){ return __builtin_amdgcn_rcpf(x); }
// fast sigmoid / tanh: v_exp + v_rcp, ~1e-6 rel err (<< bf16 gate noise)
__device__ __forceinline__ float fsigm(float x){ return frcp(1.0f + __expf(-x)); }
__device__ __forceinline__ float ftanh(float x){ return 1.0f - 2.0f*frcp(1.0f + __expf(2.0f*x)); }

// ---------------- pre-swizzle B = [Wi;Wh] (f32) into bf16 MFMA fragment order
// Bsw[((kc*32+ct)*64 + lane)*8 + j] = bf16(Bcat[kc*32 + (lane>>4)*8 + j][ct*16 + (lane&15)])
__global__ void kswz(const float* __restrict__ Wi0, const float* __restrict__ Wh0,
                     const float* __restrict__ Wi1, const float* __restrict__ Wh1,
                     unsigned short* __restrict__ Bsw0, unsigned short* __restrict__ Bsw1){
  int bid = blockIdx.x;            // 0..511
  int layer = bid >> 8;
  int kc = (bid >> 5) & 7;
  int ct = bid & 31;
  int lane = threadIdx.x;          // 0..63
  const float* Wi = layer ? Wi1 : Wi0;
  const float* Wh = layer ? Wh1 : Wh0;
  unsigned short* dst = layer ? Bsw1 : Bsw0;
  int col = ct*16 + (lane & 15);
  int kbase = kc*32 + (lane >> 4)*8;
  size_t o = ((size_t)(kc*32 + ct)*64 + (size_t)lane)*8;
  #pragma unroll
  for (int j = 0; j < 8; j++){
    int k = kbase + j;
    dst[o + j] = f2b((k < 128) ? Wi[k*512 + col] : Wh[(k-128)*512 + col]);
  }
}

// ---------------- fused 2-layer LSTM, persistent + software-pipelined -------
// Grid: 512 blocks (2/CU) x 512 threads (8 waves); each block walks 4 tiles of
// 32 rows (grid-stride). Double-buffered LDS A/H tiles: tile t+1's global
// loads are ISSUED at the top of tile t's compute and committed to the other
// buffer at the end -> HBM stays busy during the whole GEMM span.
// Global c/h stores PREDICATED OFF at exit/raise NODE rows (mask_h semantics;
// replaces ksave/krestore). State after this kernel == masked contrib, which
// is exactly what kdec/kagg must consume.
#define ROWSB 32
#define NTILES (BN/ROWSB)   // 2048
#define GRID 512
#define PA 264   // ushorts/row of A tile: 256 + 8 pad
#define PH 136   // ushorts/row of H tiles: 128 + 8 pad

__global__ __launch_bounds__(512, 4) void klstm2(
    const float* __restrict__ ne,
    float* __restrict__ c0, float* __restrict__ h0,
    float* __restrict__ c1, float* __restrict__ h1,
    const unsigned short* __restrict__ Bsw0, const float* __restrict__ b0,
    const unsigned short* __restrict__ Bsw1, const float* __restrict__ b1,
    const int* __restrict__ exit_idx, const int* __restrict__ raise_idx,
    const int* __restrict__ step_limits, const int* __restrict__ cur_step)
{
  __shared__ unsigned short ldsA[2][ROWSB*PA];   // [ne | h0_old] bf16, dbuf
  __shared__ unsigned short ldsH[2][ROWSB*PH];   // h1_old bf16, dbuf
  __shared__ unsigned short ldsG[ROWSB*PH];      // h0_new bf16 (per-tile)

  int tid = threadIdx.x;
  int wid = tid >> 6, lane = tid & 63;
  int quad = lane >> 4, l16 = lane & 15;
  int ch = wid*16 + l16;            // channel within each gate (0..127)
  int curstep = cur_step[0];

  // per-thread staging coordinates (constant across tiles)
  int arow[4], achk[4], hrow[2], hchk[2];
  #pragma unroll
  for (int p = 0; p < 4; p++){ int idx = p*512 + tid; arow[p] = idx >> 6; achk[p] = idx & 63; }
  #pragma unroll
  for (int p = 0; p < 2; p++){ int idx = p*512 + tid; hrow[p] = idx >> 5; hchk[p] = idx & 31; }

  const v8s* Bv0 = (const v8s*)Bsw0;
  const v8s* Bv1 = (const v8s*)Bsw1;

  float4 rgA[4], rgH[2];

  // ---- prologue: stage tile t0 into buffer 0 ----
  int t0 = blockIdx.x;
  if (curstep < step_limits[t0 >> 6]){
    int rowbase = t0 * ROWSB;
    #pragma unroll
    for (int p = 0; p < 4; p++){
      size_t g = (size_t)(rowbase + arow[p])*128 + (achk[p] & 31)*4;
      rgA[p] = (achk[p] < 32) ? *(const float4*)(ne + g) : *(const float4*)(h0 + g);
    }
    #pragma unroll
    for (int p = 0; p < 2; p++)
      rgH[p] = *(const float4*)(h1 + (size_t)(rowbase + hrow[p])*128 + hchk[p]*4);
    #pragma unroll
    for (int p = 0; p < 4; p++){
      uint2 w; w.x = pk2(rgA[p].x, rgA[p].y); w.y = pk2(rgA[p].z, rgA[p].w);
      *(uint2*)&ldsA[0][arow[p]*PA + achk[p]*4] = w;
    }
    #pragma unroll
    for (int p = 0; p < 2; p++){
      uint2 w; w.x = pk2(rgH[p].x, rgH[p].y); w.y = pk2(rgH[p].z, rgH[p].w);
      *(uint2*)&ldsH[0][hrow[p]*PH + hchk[p]*4] = w;
    }
  }
  __syncthreads();

  int cur = 0;
  for (int t = t0; t < NTILES; t += GRID){
    int tn = t + GRID;
    bool alive_c = (curstep < step_limits[t >> 6]);
    bool alive_n = (tn < NTILES) && (curstep < step_limits[tn >> 6]);
    int rowbase = t * ROWSB;
    int b = rowbase >> 11;

    // ---- issue tile t+1 global loads NOW; they fly during both GEMMs ----
    if (alive_n){
      int rb2 = tn * ROWSB;
      #pragma unroll
      for (int p = 0; p < 4; p++){
        size_t g = (size_t)(rb2 + arow[p])*128 + (achk[p] & 31)*4;
        rgA[p] = (achk[p] < 32) ? *(const float4*)(ne + g) : *(const float4*)(h0 + g);
      }
      #pragma unroll
      for (int p = 0; p < 2; p++)
        rgH[p] = *(const float4*)(h1 + (size_t)(rb2 + hrow[p])*128 + hchk[p]*4);
    }

    v4f acc[2][4] = {};
    float cpre[8], bias[4];
    int e_row = 0, r_row = 0;

    if (alive_c){
      e_row = exit_idx[b]; r_row = raise_idx[b];   // NODE indices (0..2047)
      #pragma unroll
      for (int rt = 0; rt < 2; rt++)
        #pragma unroll
        for (int r = 0; r < 4; r++)
          cpre[rt*4+r] = c0[((size_t)rowbase + rt*16 + quad*4 + r)*128 + ch];
      #pragma unroll
      for (int g = 0; g < 4; g++) bias[g] = b0[g*128 + ch];

      // ============ layer 0: gates = [ne|h0_old] @ B0 ============
      #pragma unroll
      for (int kc = 0; kc < 8; kc++){
        v8s f0 = Bv0[(size_t)(kc*32 + 0*8 + wid)*64 + lane];
        v8s f1 = Bv0[(size_t)(kc*32 + 1*8 + wid)*64 + lane];
        v8s f2 = Bv0[(size_t)(kc*32 + 2*8 + wid)*64 + lane];
        v8s f3 = Bv0[(size_t)(kc*32 + 3*8 + wid)*64 + lane];
        v8s a0 = *(const v8s*)&ldsA[cur][(0*16 + l16)*PA + kc*32 + quad*8];
        v8s a1 = *(const v8s*)&ldsA[cur][(1*16 + l16)*PA + kc*32 + quad*8];
        acc[0][0] = __builtin_amdgcn_mfma_f32_16x16x32_bf16(a0, f0, acc[0][0], 0,0,0);
        acc[1][0] = __builtin_amdgcn_mfma_f32_16x16x32_bf16(a1, f0, acc[1][0], 0,0,0);
        acc[0][1] = __builtin_amdgcn_mfma_f32_16x16x32_bf16(a0, f1, acc[0][1], 0,0,0);
        acc[1][1] = __builtin_amdgcn_mfma_f32_16x16x32_bf16(a1, f1, acc[1][1], 0,0,0);
        acc[0][2] = __builtin_amdgcn_mfma_f32_16x16x32_bf16(a0, f2, acc[0][2], 0,0,0);
        acc[1][2] = __builtin_amdgcn_mfma_f32_16x16x32_bf16(a1, f2, acc[1][2], 0,0,0);
        acc[0][3] = __builtin_amdgcn_mfma_f32_16x16x32_bf16(a0, f3, acc[0][3], 0,0,0);
        acc[1][3] = __builtin_amdgcn_mfma_f32_16x16x32_bf16(a1, f3, acc[1][3], 0,0,0);
      }

      // ---- epilogue 0: LSTM update; h0_new -> ldsG ----
      #pragma unroll
      for (int rt = 0; rt < 2; rt++){
        #pragma unroll
        for (int r = 0; r < 4; r++){
          int k = rt*4 + r;
          int lrow = rt*16 + quad*4 + r;
          int grow = rowbase + lrow;
          int node = grow & 2047;
          bool special = (node == e_row) || (node == r_row);
          float iv = acc[rt][0][r] + bias[0];
          float fv = acc[rt][1][r] + bias[1];
          float gv = acc[rt][2][r] + bias[2];
          float ov = acc[rt][3][r] + bias[3];
          float cn = fsigm(fv)*cpre[k] + fsigm(iv)*ftanh(gv);
          float hn = fsigm(ov)*ftanh(cn);
          if (!special){
            c0[(size_t)grow*128 + ch] = cn;
            h0[(size_t)grow*128 + ch] = hn;
          }
          ldsG[lrow*PH + ch] = f2b(hn);   // layer-1 A operand (UNMASKED h0n, per ref)
        }
      }

      // ---- prefetch c1 rows + layer-1 bias (hidden by barrier+GEMM1) ----
      #pragma unroll
      for (int rt = 0; rt < 2; rt++)
        #pragma unroll
        for (int r = 0; r < 4; r++)
          cpre[rt*4+r] = c1[((size_t)rowbase + rt*16 + quad*4 + r)*128 + ch];
      #pragma unroll
      for (int g = 0; g < 4; g++) bias[g] = b1[g*128 + ch];
    }
    __syncthreads();   // ldsG complete (ldsA[cur]/ldsH[cur] reads of THIS tile pending GEMM1 for H)

    if (alive_c){
      // ============ layer 1: gates = [h0_new | h1_old] @ B1 ============
      #pragma unroll
      for (int rt = 0; rt < 2; rt++)
        #pragma unroll
        for (int g = 0; g < 4; g++)
          acc[rt][g] = (v4f){0.f, 0.f, 0.f, 0.f};
      #pragma unroll
      for (int kc = 0; kc < 8; kc++){
        v8s f0 = Bv1[(size_t)(kc*32 + 0*8 + wid)*64 + lane];
        v8s f1 = Bv1[(size_t)(kc*32 + 1*8 + wid)*64 + lane];
        v8s f2 = Bv1[(size_t)(kc*32 + 2*8 + wid)*64 + lane];
        v8s f3 = Bv1[(size_t)(kc*32 + 3*8 + wid)*64 + lane];
        v8s a0, a1;
        if (kc < 4){
          a0 = *(const v8s*)&ldsG[(0*16 + l16)*PH + kc*32 + quad*8];
          a1 = *(const v8s*)&ldsG[(1*16 + l16)*PH + kc*32 + quad*8];
        } else {
          a0 = *(const v8s*)&ldsH[cur][(0*16 + l16)*PH + (kc-4)*32 + quad*8];
          a1 = *(const v8s*)&ldsH[cur][(1*16 + l16)*PH + (kc-4)*32 + quad*8];
        }
        acc[0][0] = __builtin_amdgcn_mfma_f32_16x16x32_bf16(a0, f0, acc[0][0], 0,0,0);
        acc[1][0] = __builtin_amdgcn_mfma_f32_16x16x32_bf16(a1, f0, acc[1][0], 0,0,0);
        acc[0][1] = __builtin_amdgcn_mfma_f32_16x16x32_bf16(a0, f1, acc[0][1], 0,0,0);
        acc[1][1] = __builtin_amdgcn_mfma_f32_16x16x32_bf16(a1, f1, acc[1][1], 0,0,0);
        acc[0][2] = __builtin_amdgcn_mfma_f32_16x16x32_bf16(a0, f2, acc[0][2], 0,0,0);
        acc[1][2] = __builtin_amdgcn_mfma_f32_16x16x32_bf16(a1, f2, acc[1][2], 0,0,0);
        acc[0][3] = __builtin_amdgcn_mfma_f32_16x16x32_bf16(a0, f3, acc[0][3], 0,0,0);
        acc[1][3] = __builtin_amdgcn_mfma_f32_16x16x32_bf16(a1, f3, acc[1][3], 0,0,0);
      }

      // ---- epilogue 1 ----
      #pragma unroll
      for (int rt = 0; rt < 2; rt++){
        #pragma unroll
        for (int r = 0; r < 4; r++){
          int k = rt*4 + r;
          int grow = rowbase + rt*16 + quad*4 + r;
          int node = grow & 2047;
          bool special = (node == e_row) || (node == r_row);
          float iv = acc[rt][0][r] + bias[0];
          float fv = acc[rt][1][r] + bias[1];
          float gv = acc[rt][2][r] + bias[2];
          float ov = acc[rt][3][r] + bias[3];
          float cn = fsigm(fv)*cpre[k] + fsigm(iv)*ftanh(gv);
          float hn = fsigm(ov)*ftanh(cn);
          if (!special){
            c1[(size_t)grow*128 + ch] = cn;
            h1[(size_t)grow*128 + ch] = hn;
          }
        }
      }
    }

    // ---- commit tile t+1 stage into the other buffer ----
    if (alive_n){
      #pragma unroll
      for (int p = 0; p < 4; p++){
        uint2 w; w.x = pk2(rgA[p].x, rgA[p].y); w.y = pk2(rgA[p].z, rgA[p].w);
        *(uint2*)&ldsA[cur^1][arow[p]*PA + achk[p]*4] = w;
      }
      #pragma unroll
      for (int p = 0; p < 2; p++){
        uint2 w; w.x = pk2(rgH[p].x, rgH[p].y); w.y = pk2(rgH[p].z, rgH[p].w);
        *(uint2*)&ldsH[cur^1][hrow[p]*PH + hchk[p]*4] = w;
      }
    }
    __syncthreads();   // next buffer staged; ldsG reads done -> reusable
    cur ^= 1;
  }
}

// ---------------- decisions: softmax(hs @ W) -> edge weights wr/wt/wf -------
// state buffers hold MASKED contrib (old state at exit/raise rows), which is
// exactly the reference's hs_emb. Also counts CSR edges in idle lanes.
__global__ __launch_bounds__(256) void kdec(
    const float* __restrict__ c0, const float* __restrict__ h0,
    const float* __restrict__ c1, const float* __restrict__ h1,
    const float* __restrict__ Wr, const float* __restrict__ br,
    const float* __restrict__ Wb, const float* __restrict__ bb,
    const float* __restrict__ ip,
    const int* __restrict__ exit_idx, const int* __restrict__ raise_idx,
    const int* __restrict__ ri, const int* __restrict__ ti, const int* __restrict__ fi,
    int* __restrict__ counts,
    float* __restrict__ wbuf)
{
  int tid = threadIdx.x;
  int wid = tid >> 6, lane = tid & 63;
  int gid = blockIdx.x*4 + wid;          // node id
  int b = gid >> 11, n = gid & 2047;

  const float* bufs[4] = {c0, h0, c1, h1};
  const float* hb = bufs[lane >> 4] + (size_t)gid*128 + (lane & 15)*8;
  float4 hv0 = *(const float4*)hb;
  float4 hv1 = *(const float4*)(hb + 4);
  float hv[8] = {hv0.x, hv0.y, hv0.z, hv0.w, hv1.x, hv1.y, hv1.z, hv1.w};
  const float* wrp = Wr + lane*16;
  const float* wbp = Wb + lane*16;
  float r0=0.f, r1=0.f, q0=0.f, q1=0.f;
  #pragma unroll
  for (int j = 0; j < 8; j++){
    float h = hv[j];
    r0 += h * wrp[j*2];  r1 += h * wrp[j*2+1];
    q0 += h * wbp[j*2];  q1 += h * wbp[j*2+1];
  }
  #pragma unroll
  for (int off = 32; off > 0; off >>= 1){
    r0 += __shfl_xor(r0, off, 64);
    r1 += __shfl_xor(r1, off, 64);
    q0 += __shfl_xor(q0, off, 64);
    q1 += __shfl_xor(q1, off, 64);
  }
  if (lane == 0){
    r0 += br[0]; r1 += br[1];
    q0 += bb[0]; q1 += bb[1];
    float pr, pn;
    if (n == exit_idx[b] || n == raise_idx[b]){ pr = 0.f; pn = 1.f; }
    else {
      float m = fmaxf(r0, r1);
      float e0 = __expf(r0 - m), e1 = __expf(r1 - m);
      pr = e0 / (e0 + e1); pn = e1 / (e0 + e1);
    }
    float m2 = fmaxf(q0, q1);
    float f0 = __expf(q0 - m2), f1 = __expf(q1 - m2);
    float pt = f0 / (f0 + f1), pf = f1 / (f0 + f1);
    float ipv = ip[gid];
    wbuf[0*BN + gid] = pr * ipv;
    wbuf[1*BN + gid] = pn * pt * ipv;
    wbuf[2*BN + gid] = pn * pf * ipv;
  } else if (lane == 1){
    atomicAdd(&counts[(b<<11) + ri[gid]], 1);
  } else if (lane == 2){
    atomicAdd(&counts[(b<<11) + ti[gid]], 1);
  } else if (lane == 3){
    atomicAdd(&counts[(b<<11) + fi[gid]], 1);
  }
}

// ---------------- CSR build: scan (also zeroes cursor) / fill ----------------
__global__ __launch_bounds__(256) void kscan(const int* __restrict__ counts,
                                             int* __restrict__ offsets,
                                             int* __restrict__ cursor){
  __shared__ int lds[256];
  int b = blockIdx.x, tid = threadIdx.x;
  const int* c = counts + b*NN;
  int* o = offsets + b*NN;
  int* cu = cursor + b*NN;
  int v[8]; int s = 0;
  #pragma unroll
  for (int i = 0; i < 8; i++){ v[i] = c[tid*8+i]; s += v[i]; cu[tid*8+i] = 0; }
  lds[tid] = s;
  __syncthreads();
  if (tid == 0){
    int run = 0;
    for (int t = 0; t < 256; t++){ int tmp = lds[t]; lds[t] = run; run += tmp; }
  }
  __syncthreads();
  int off = lds[tid];
  #pragma unroll
  for (int i = 0; i < 8; i++){ o[tid*8+i] = off; off += v[i]; }
}

__global__ void kfill(const int* __restrict__ ri, const int* __restrict__ ti,
                      const int* __restrict__ fi, const int* __restrict__ offsets,
                      int* __restrict__ cursor, unsigned short* __restrict__ edges){
  int gid = blockIdx.x*256 + threadIdx.x;
  int b = gid >> 11, n = gid & 2047;
  size_t ebase = (size_t)b*3*NN;
  int t0 = ri[gid]; int p0 = atomicAdd(&cursor[b*NN+t0], 1);
  edges[ebase + offsets[b*NN+t0] + p0] = (unsigned short)(n);
  int t1 = ti[gid]; int p1 = atomicAdd(&cursor[b*NN+t1], 1);
  edges[ebase + offsets[b*NN+t1] + p1] = (unsigned short)(n | (1<<11));
  int t2 = fi[gid]; int p2 = atomicAdd(&cursor[b*NN+t2], 1);
  edges[ebase + offsets[b*NN+t2] + p2] = (unsigned short)(n | (2<<11));
}

// ---------------- gather + normalize + output (all batches) -----------------
__global__ __launch_bounds__(128) void kagg(
    const float* __restrict__ c0, const float* __restrict__ h0,
    const float* __restrict__ c1, const float* __restrict__ h1,
    const float* __restrict__ ip,
    const float* __restrict__ wbuf, const unsigned short* __restrict__ edges,
    const int* __restrict__ counts, const int* __restrict__ offsets,
    const int* __restrict__ step_limits, const int* __restrict__ cur_step,
    float* __restrict__ out)
{
  int gid = blockIdx.x;            // b*N + j
  int b = gid >> 11;
  int tid = threadIdx.x;           // 0..127, channels tid*4..tid*4+3
  size_t obase = (size_t)gid*513;
  const float* bufs[4] = {c0, h0, c1, h1};

  if (cur_step[0] >= step_limits[b]){       // done: copy old state + old ip
    int c = tid*4;
    const float* s = bufs[c >> 7];
    size_t rb = (size_t)gid*128 + (c & 127);
    out[obase + c+0] = s[rb+0];
    out[obase + c+1] = s[rb+1];
    out[obase + c+2] = s[rb+2];
    out[obase + c+3] = s[rb+3];
    if (tid == 0) out[obase + 512] = ip[gid];
    return;
  }

  int cnt = counts[gid], off = offsets[gid];
  const unsigned short* eb = edges + (size_t)b*3*NN + off;
  const float* sb = bufs[tid >> 5];
  int coff = (tid & 31)*4;
  float a0=0.f, a1=0.f, a2=0.f, a3=0.f, ipn=0.f;
  int pk = (cnt > 0) ? eb[0] : 0;
  for (int e = 0; e < cnt; e++){
    int pkn = (e+1 < cnt) ? eb[e+1] : 0;     // prefetch next edge
    int n = pk & 2047, et = pk >> 11;
    float w = wbuf[et*BN + (b<<11) + n];
    float4 sv = *(const float4*)(sb + ((size_t)(b<<11) + n)*128 + coff);
    ipn += w;
    a0 += w * sv.x;
    a1 += w * sv.y;
    a2 += w * sv.z;
    a3 += w * sv.w;
    pk = pkn;
  }
  int c = tid*4;
  float inv = 1.0f / (ipn + 1e-7f);
  out[obase + c+0] = a0*inv;
  out[obase + c+1] = a1*inv;
  out[obase + c+2] = a2*inv;
  out[obase + c+3] = a3*inv;
  if (tid == 0) out[obase + 512] = ipn;
}

extern "C" void kernel_launch(void* const* d_in, const int* in_sizes, int n_in,
                              void* d_out, int out_size, void* d_ws, size_t ws_size,
                              hipStream_t stream){
  const float* ne  = (const float*)d_in[0];
  float* c0  = (float*)d_in[1];   // updated in place (harness restores before every launch)
  float* h0  = (float*)d_in[2];
  float* c1  = (float*)d_in[3];
  float* h1  = (float*)d_in[4];
  const float* ip  = (const float*)d_in[5];
  const float* Wi0 = (const float*)d_in[6];
  const float* Wh0 = (const float*)d_in[7];
  const float* b0  = (const float*)d_in[8];
  const float* Wi1 = (const float*)d_in[9];
  const float* Wh1 = (const float*)d_in[10];
  const float* b1  = (const float*)d_in[11];
  const float* Wr  = (const float*)d_in[12];
  const float* br  = (const float*)d_in[13];
  const float* Wb  = (const float*)d_in[14];
  const float* bb  = (const float*)d_in[15];
  const int* ti  = (const int*)d_in[16];
  const int* fi  = (const int*)d_in[17];
  const int* ri  = (const int*)d_in[18];
  const int* ei  = (const int*)d_in[19];
  const int* rni = (const int*)d_in[20];
  const int* sl  = (const int*)d_in[21];
  const int* cs  = (const int*)d_in[22];
  float* out = (float*)d_out;

  // --- ws layout ---
  uint8_t* ws = (uint8_t*)d_ws;
  unsigned short* Bsw0    = (unsigned short*)(ws + 0);         // 262144 B
  unsigned short* Bsw1    = (unsigned short*)(ws + 262144);    // 262144 B
  float*          wbuf    = (float*)(ws + 655360);             // 786432 B
  int*            counts  = (int*)(ws + 1441792);              // 262144 B
  int*            offsets = (int*)(ws + 1703936);              // 262144 B
  int*            cursor  = (int*)(ws + 1966080);              // 262144 B
  unsigned short* edges   = (unsigned short*)(ws + 2228224);   // 393216 B

  hipMemsetAsync(counts, 0, BN*sizeof(int), stream);

  kswz<<<512, 64, 0, stream>>>(Wi0, Wh0, Wi1, Wh1, Bsw0, Bsw1);

  // persistent pipelined 2-layer LSTM; skips done batches; skips writes at
  // exit/raise rows (keeps old state there)
  klstm2<<<GRID, 512, 0, stream>>>(ne, c0, h0, c1, h1, Bsw0, b0, Bsw1, b1,
                                   ei, rni, sl, cs);

  // decisions + edge counting (reads masked contrib from global state)
  kdec<<<BN/4, 256, 0, stream>>>(c0, h0, c1, h1, Wr, br, Wb, bb, ip, ei, rni,
                                 ri, ti, fi, counts, wbuf);

  kscan<<<BB, 256, 0, stream>>>(counts, offsets, cursor);
  kfill<<<BN/256, 256, 0, stream>>>(ri, ti, fi, offsets, cursor, edges);

  kagg<<<BN, 128, 0, stream>>>(c0, h0, c1, h1, ip, wbuf, edges, counts, offsets,
                               sl, cs, out);
}

// Round 7
// 441.444 us; speedup vs baseline: 1.5177x; 1.5177x over previous
//
#include <hip/hip_runtime.h>
#include <stdint.h>

#define BB 32
#define NN 2048
#define HH 128
#define BN (BB*NN)

typedef short v8s __attribute__((ext_vector_type(8)));
typedef float v4f __attribute__((ext_vector_type(4)));

__device__ __forceinline__ unsigned short f2b(float f){
  union { float f; unsigned int i; } v; v.f = f;
  unsigned int x = v.i;
  unsigned int r = x + 0x7FFFu + ((x >> 16) & 1u);   // RNE f32 -> bf16
  return (unsigned short)(r >> 16);
}
__device__ __forceinline__ unsigned int pk2(float a, float b){
  return (unsigned int)f2b(a) | ((unsigned int)f2b(b) << 16);
}
__device__ __forceinline__ float b2f(unsigned int s){
  union { unsigned int i; float f; } v; v.i = s << 16; return v.f;
}
__device__ __forceinline__ float frcp(float x){ return __builtin_amdgcn_rcpf(x); }
// fast sigmoid / tanh: v_exp + v_rcp, ~1e-6 rel err (<< bf16 gate noise)
__device__ __forceinline__ float fsigm(float x){ return frcp(1.0f + __expf(-x)); }
__device__ __forceinline__ float ftanh(float x){ return 1.0f - 2.0f*frcp(1.0f + __expf(2.0f*x)); }

// ---------------- pre-swizzle B = [Wi;Wh] (f32) into bf16 MFMA fragment order
__global__ void kswz(const float* __restrict__ Wi0, const float* __restrict__ Wh0,
                     const float* __restrict__ Wi1, const float* __restrict__ Wh1,
                     unsigned short* __restrict__ Bsw0, unsigned short* __restrict__ Bsw1){
  int bid = blockIdx.x;            // 0..511
  int layer = bid >> 8;
  int kc = (bid >> 5) & 7;
  int ct = bid & 31;
  int lane = threadIdx.x;          // 0..63
  const float* Wi = layer ? Wi1 : Wi0;
  const float* Wh = layer ? Wh1 : Wh0;
  unsigned short* dst = layer ? Bsw1 : Bsw0;
  int col = ct*16 + (lane & 15);
  int kbase = kc*32 + (lane >> 4)*8;
  size_t o = ((size_t)(kc*32 + ct)*64 + (size_t)lane)*8;
  #pragma unroll
  for (int j = 0; j < 8; j++){
    int k = kbase + j;
    dst[o + j] = f2b((k < 128) ? Wi[k*512 + col] : Wh[(k-128)*512 + col]);
  }
}

// ---------------- fused 2-layer LSTM (r2 schedule; bf16 state sink) ---------
// Block: 32 rows, 512 threads (8 waves). Wave w owns channels w*16..w*16+15 of
// every gate (acc 32 regs/thread). NOTHING extra stays live across a GEMM
// (rounds 4-6 lesson: spills). Stores: if useb, masked contrib states go to
// bf16 ws arrays ONLY (f32 state buffers untouched -> done-path reads old);
// else f32 in-place with predicated-off special rows (r5 behavior).
#define ROWSB 32
#define PA 264   // ushorts/row of A tile: 256 + 8 pad
#define PH 136   // ushorts/row of H tiles: 128 + 8 pad

__global__ __launch_bounds__(512, 4) void klstm2(
    const float* __restrict__ ne,
    float* __restrict__ c0, float* __restrict__ h0,
    float* __restrict__ c1, float* __restrict__ h1,
    unsigned short* __restrict__ sc0, unsigned short* __restrict__ sh0,
    unsigned short* __restrict__ sc1, unsigned short* __restrict__ sh1,
    const unsigned short* __restrict__ Bsw0, const float* __restrict__ b0,
    const unsigned short* __restrict__ Bsw1, const float* __restrict__ b1,
    const int* __restrict__ exit_idx, const int* __restrict__ raise_idx,
    const int* __restrict__ step_limits, const int* __restrict__ cur_step,
    int useb)
{
  __shared__ unsigned short ldsA[ROWSB*PA];   // [ne | h0_old] bf16
  __shared__ unsigned short ldsH[ROWSB*PH];   // h1_old bf16
  __shared__ unsigned short ldsG[ROWSB*PH];   // h0_new bf16

  int rowbase = blockIdx.x * ROWSB;           // 32 rows, never crosses a batch
  int b = rowbase >> 11;
  if (cur_step[0] >= step_limits[b]) return;  // done batch: keep old states

  int tid = threadIdx.x;
  int wid = tid >> 6, lane = tid & 63;
  int quad = lane >> 4, l16 = lane & 15;
  int ch = wid*16 + l16;            // channel within each gate (0..127)
  int e_row = exit_idx[b], r_row = raise_idx[b];   // NODE indices (0..2047)

  // ---- stage A0 = bf16([ne | h0_old]) : 4 float4 per thread ----
  #pragma unroll
  for (int p = 0; p < 4; p++){
    int idx = p*512 + tid;
    int row = idx >> 6, chunk = idx & 63;     // chunk = float4 index (0..63)
    size_t g = (size_t)(rowbase + row)*128 + (chunk & 31)*4;
    float4 v = (chunk < 32) ? *(const float4*)(ne + g) : *(const float4*)(h0 + g);
    uint2 w; w.x = pk2(v.x, v.y); w.y = pk2(v.z, v.w);
    *(uint2*)&ldsA[row*PA + chunk*4] = w;
  }
  __syncthreads();

  // ---- prefetch c0 rows + layer-0 biases (independent of LDS; hidden by GEMM0)
  float cpre[8], bias[4];
  #pragma unroll
  for (int rt = 0; rt < 2; rt++)
    #pragma unroll
    for (int r = 0; r < 4; r++)
      cpre[rt*4+r] = c0[((size_t)rowbase + rt*16 + quad*4 + r)*128 + ch];
  #pragma unroll
  for (int g = 0; g < 4; g++) bias[g] = b0[g*128 + ch];

  // ---- stage H1 = bf16(h1_old) during GEMM0's shadow (consumed after b2) ----
  #pragma unroll
  for (int p = 0; p < 2; p++){
    int idx = p*512 + tid;
    int row = idx >> 5, chunk = idx & 31;
    float4 v = *(const float4*)(h1 + (size_t)(rowbase + row)*128 + chunk*4);
    uint2 w; w.x = pk2(v.x, v.y); w.y = pk2(v.z, v.w);
    *(uint2*)&ldsH[row*PH + chunk*4] = w;
  }

  // ================= layer 0: gates = [ne|h0_old] @ B0 =================
  const v8s* Bv0 = (const v8s*)Bsw0;
  v4f acc[2][4] = {};
  v8s bc[4], bn[4];
  #pragma unroll
  for (int g = 0; g < 4; g++) bc[g] = Bv0[(size_t)(g*8 + wid)*64 + lane];
  #pragma unroll
  for (int kc = 0; kc < 8; kc++){
    if (kc < 7){
      #pragma unroll
      for (int g = 0; g < 4; g++) bn[g] = Bv0[(size_t)((kc+1)*32 + g*8 + wid)*64 + lane];
    }
    v8s a0 = *(const v8s*)&ldsA[(0*16 + l16)*PA + kc*32 + quad*8];
    v8s a1 = *(const v8s*)&ldsA[(1*16 + l16)*PA + kc*32 + quad*8];
    #pragma unroll
    for (int g = 0; g < 4; g++){
      acc[0][g] = __builtin_amdgcn_mfma_f32_16x16x32_bf16(a0, bc[g], acc[0][g], 0,0,0);
      acc[1][g] = __builtin_amdgcn_mfma_f32_16x16x32_bf16(a1, bc[g], acc[1][g], 0,0,0);
    }
    #pragma unroll
    for (int g = 0; g < 4; g++) bc[g] = bn[g];
  }

  // ---- epilogue 0: LSTM update; h0_new -> ldsG; state -> bf16 ws or f32 ----
  #pragma unroll
  for (int rt = 0; rt < 2; rt++){
    #pragma unroll
    for (int r = 0; r < 4; r++){
      int k = rt*4 + r;
      int lrow = rt*16 + quad*4 + r;
      int grow = rowbase + lrow;
      int node = grow & 2047;
      bool special = (node == e_row) || (node == r_row);
      float iv = acc[rt][0][r] + bias[0];
      float fv = acc[rt][1][r] + bias[1];
      float gv = acc[rt][2][r] + bias[2];
      float ov = acc[rt][3][r] + bias[3];
      float cn = fsigm(fv)*cpre[k] + fsigm(iv)*ftanh(gv);
      float hn = fsigm(ov)*ftanh(cn);
      if (useb){
        // masked contrib in bf16: special rows hold OLD state
        sc0[(size_t)grow*128 + ch] = special ? f2b(cpre[k]) : f2b(cn);
        sh0[(size_t)grow*128 + ch] = special ? ldsA[lrow*PA + 128 + ch] : f2b(hn);
      } else if (!special){
        c0[(size_t)grow*128 + ch] = cn;
        h0[(size_t)grow*128 + ch] = hn;
      }
      ldsG[lrow*PH + ch] = f2b(hn);   // layer-1 A operand (UNMASKED h0n, per ref)
    }
  }

  // ---- prefetch c1 rows + layer-1 bias + first B1 frags (pre-barrier) ----
  #pragma unroll
  for (int rt = 0; rt < 2; rt++)
    #pragma unroll
    for (int r = 0; r < 4; r++)
      cpre[rt*4+r] = c1[((size_t)rowbase + rt*16 + quad*4 + r)*128 + ch];
  #pragma unroll
  for (int g = 0; g < 4; g++) bias[g] = b1[g*128 + ch];
  const v8s* Bv1 = (const v8s*)Bsw1;
  #pragma unroll
  for (int g = 0; g < 4; g++) bc[g] = Bv1[(size_t)(g*8 + wid)*64 + lane];

  __syncthreads();   // h0_new + h1_old LDS tiles complete

  // ================= layer 1: gates = [h0_new | h1_old] @ B1 =================
  #pragma unroll
  for (int rt = 0; rt < 2; rt++)
    #pragma unroll
    for (int g = 0; g < 4; g++)
      acc[rt][g] = (v4f){0.f, 0.f, 0.f, 0.f};
  #pragma unroll
  for (int kc = 0; kc < 8; kc++){
    if (kc < 7){
      #pragma unroll
      for (int g = 0; g < 4; g++) bn[g] = Bv1[(size_t)((kc+1)*32 + g*8 + wid)*64 + lane];
    }
    v8s a0, a1;
    if (kc < 4){
      a0 = *(const v8s*)&ldsG[(0*16 + l16)*PH + kc*32 + quad*8];
      a1 = *(const v8s*)&ldsG[(1*16 + l16)*PH + kc*32 + quad*8];
    } else {
      a0 = *(const v8s*)&ldsH[(0*16 + l16)*PH + (kc-4)*32 + quad*8];
      a1 = *(const v8s*)&ldsH[(1*16 + l16)*PH + (kc-4)*32 + quad*8];
    }
    #pragma unroll
    for (int g = 0; g < 4; g++){
      acc[0][g] = __builtin_amdgcn_mfma_f32_16x16x32_bf16(a0, bc[g], acc[0][g], 0,0,0);
      acc[1][g] = __builtin_amdgcn_mfma_f32_16x16x32_bf16(a1, bc[g], acc[1][g], 0,0,0);
    }
    #pragma unroll
    for (int g = 0; g < 4; g++) bc[g] = bn[g];
  }

  // ---- epilogue 1 ----
  #pragma unroll
  for (int rt = 0; rt < 2; rt++){
    #pragma unroll
    for (int r = 0; r < 4; r++){
      int k = rt*4 + r;
      int lrow = rt*16 + quad*4 + r;
      int grow = rowbase + lrow;
      int node = grow & 2047;
      bool special = (node == e_row) || (node == r_row);
      float iv = acc[rt][0][r] + bias[0];
      float fv = acc[rt][1][r] + bias[1];
      float gv = acc[rt][2][r] + bias[2];
      float ov = acc[rt][3][r] + bias[3];
      float cn = fsigm(fv)*cpre[k] + fsigm(iv)*ftanh(gv);
      float hn = fsigm(ov)*ftanh(cn);
      if (useb){
        sc1[(size_t)grow*128 + ch] = special ? f2b(cpre[k]) : f2b(cn);
        sh1[(size_t)grow*128 + ch] = special ? ldsH[lrow*PH + ch] : f2b(hn);
      } else if (!special){
        c1[(size_t)grow*128 + ch] = cn;
        h1[(size_t)grow*128 + ch] = hn;
      }
    }
  }
}

// ---------------- decisions: softmax(hs @ W) -> edge weights wr/wt/wf -------
// reads masked contrib (bf16 ws if useb else f32 state). Counts CSR edges in
// idle lanes.
__global__ __launch_bounds__(256) void kdec(
    const float* __restrict__ c0, const float* __restrict__ h0,
    const float* __restrict__ c1, const float* __restrict__ h1,
    const unsigned short* __restrict__ sc0, const unsigned short* __restrict__ sh0,
    const unsigned short* __restrict__ sc1, const unsigned short* __restrict__ sh1,
    const float* __restrict__ Wr, const float* __restrict__ br,
    const float* __restrict__ Wb, const float* __restrict__ bb,
    const float* __restrict__ ip,
    const int* __restrict__ exit_idx, const int* __restrict__ raise_idx,
    const int* __restrict__ ri, const int* __restrict__ ti, const int* __restrict__ fi,
    int* __restrict__ counts,
    float* __restrict__ wbuf, int useb)
{
  int tid = threadIdx.x;
  int wid = tid >> 6, lane = tid & 63;
  int gid = blockIdx.x*4 + wid;          // node id
  int b = gid >> 11, n = gid & 2047;

  float hv[8];
  if (useb){
    const unsigned short* bufs16[4] = {sc0, sh0, sc1, sh1};
    const unsigned short* hb = bufs16[lane >> 4] + (size_t)gid*128 + (lane & 15)*8;
    uint4 raw = *(const uint4*)hb;        // 8 bf16
    hv[0] = b2f(raw.x & 0xffffu); hv[1] = b2f(raw.x >> 16);
    hv[2] = b2f(raw.y & 0xffffu); hv[3] = b2f(raw.y >> 16);
    hv[4] = b2f(raw.z & 0xffffu); hv[5] = b2f(raw.z >> 16);
    hv[6] = b2f(raw.w & 0xffffu); hv[7] = b2f(raw.w >> 16);
  } else {
    const float* bufs[4] = {c0, h0, c1, h1};
    const float* hb = bufs[lane >> 4] + (size_t)gid*128 + (lane & 15)*8;
    float4 hv0 = *(const float4*)hb;
    float4 hv1 = *(const float4*)(hb + 4);
    hv[0]=hv0.x; hv[1]=hv0.y; hv[2]=hv0.z; hv[3]=hv0.w;
    hv[4]=hv1.x; hv[5]=hv1.y; hv[6]=hv1.z; hv[7]=hv1.w;
  }
  const float* wrp = Wr + lane*16;
  const float* wbp = Wb + lane*16;
  float r0=0.f, r1=0.f, q0=0.f, q1=0.f;
  #pragma unroll
  for (int j = 0; j < 8; j++){
    float h = hv[j];
    r0 += h * wrp[j*2];  r1 += h * wrp[j*2+1];
    q0 += h * wbp[j*2];  q1 += h * wbp[j*2+1];
  }
  #pragma unroll
  for (int off = 32; off > 0; off >>= 1){
    r0 += __shfl_xor(r0, off, 64);
    r1 += __shfl_xor(r1, off, 64);
    q0 += __shfl_xor(q0, off, 64);
    q1 += __shfl_xor(q1, off, 64);
  }
  if (lane == 0){
    r0 += br[0]; r1 += br[1];
    q0 += bb[0]; q1 += bb[1];
    float pr, pn;
    if (n == exit_idx[b] || n == raise_idx[b]){ pr = 0.f; pn = 1.f; }
    else {
      float m = fmaxf(r0, r1);
      float e0 = __expf(r0 - m), e1 = __expf(r1 - m);
      pr = e0 / (e0 + e1); pn = e1 / (e0 + e1);
    }
    float m2 = fmaxf(q0, q1);
    float f0 = __expf(q0 - m2), f1 = __expf(q1 - m2);
    float pt = f0 / (f0 + f1), pf = f1 / (f0 + f1);
    float ipv = ip[gid];
    wbuf[0*BN + gid] = pr * ipv;
    wbuf[1*BN + gid] = pn * pt * ipv;
    wbuf[2*BN + gid] = pn * pf * ipv;
  } else if (lane == 1){
    atomicAdd(&counts[(b<<11) + ri[gid]], 1);
  } else if (lane == 2){
    atomicAdd(&counts[(b<<11) + ti[gid]], 1);
  } else if (lane == 3){
    atomicAdd(&counts[(b<<11) + fi[gid]], 1);
  }
}

// ---------------- CSR build: scan (also zeroes cursor) / fill ----------------
__global__ __launch_bounds__(256) void kscan(const int* __restrict__ counts,
                                             int* __restrict__ offsets,
                                             int* __restrict__ cursor){
  __shared__ int lds[256];
  int b = blockIdx.x, tid = threadIdx.x;
  const int* c = counts + b*NN;
  int* o = offsets + b*NN;
  int* cu = cursor + b*NN;
  int v[8]; int s = 0;
  #pragma unroll
  for (int i = 0; i < 8; i++){ v[i] = c[tid*8+i]; s += v[i]; cu[tid*8+i] = 0; }
  lds[tid] = s;
  __syncthreads();
  if (tid == 0){
    int run = 0;
    for (int t = 0; t < 256; t++){ int tmp = lds[t]; lds[t] = run; run += tmp; }
  }
  __syncthreads();
  int off = lds[tid];
  #pragma unroll
  for (int i = 0; i < 8; i++){ o[tid*8+i] = off; off += v[i]; }
}

__global__ void kfill(const int* __restrict__ ri, const int* __restrict__ ti,
                      const int* __restrict__ fi, const int* __restrict__ offsets,
                      int* __restrict__ cursor, unsigned short* __restrict__ edges){
  int gid = blockIdx.x*256 + threadIdx.x;
  int b = gid >> 11, n = gid & 2047;
  size_t ebase = (size_t)b*3*NN;
  int t0 = ri[gid]; int p0 = atomicAdd(&cursor[b*NN+t0], 1);
  edges[ebase + offsets[b*NN+t0] + p0] = (unsigned short)(n);
  int t1 = ti[gid]; int p1 = atomicAdd(&cursor[b*NN+t1], 1);
  edges[ebase + offsets[b*NN+t1] + p1] = (unsigned short)(n | (1<<11));
  int t2 = fi[gid]; int p2 = atomicAdd(&cursor[b*NN+t2], 1);
  edges[ebase + offsets[b*NN+t2] + p2] = (unsigned short)(n | (2<<11));
}

// ---------------- gather + normalize + output (all batches) -----------------
__global__ __launch_bounds__(128) void kagg(
    const float* __restrict__ c0, const float* __restrict__ h0,
    const float* __restrict__ c1, const float* __restrict__ h1,
    const unsigned short* __restrict__ sc0, const unsigned short* __restrict__ sh0,
    const unsigned short* __restrict__ sc1, const unsigned short* __restrict__ sh1,
    const float* __restrict__ ip,
    const float* __restrict__ wbuf, const unsigned short* __restrict__ edges,
    const int* __restrict__ counts, const int* __restrict__ offsets,
    const int* __restrict__ step_limits, const int* __restrict__ cur_step,
    float* __restrict__ out, int useb)
{
  int gid = blockIdx.x;            // b*N + j
  int b = gid >> 11;
  int tid = threadIdx.x;           // 0..127, channels tid*4..tid*4+3
  size_t obase = (size_t)gid*513;
  const float* bufs[4] = {c0, h0, c1, h1};

  if (cur_step[0] >= step_limits[b]){       // done: copy old state + old ip
    int c = tid*4;
    const float* s = bufs[c >> 7];
    size_t rb = (size_t)gid*128 + (c & 127);
    out[obase + c+0] = s[rb+0];
    out[obase + c+1] = s[rb+1];
    out[obase + c+2] = s[rb+2];
    out[obase + c+3] = s[rb+3];
    if (tid == 0) out[obase + 512] = ip[gid];
    return;
  }

  int cnt = counts[gid], off = offsets[gid];
  const unsigned short* eb = edges + (size_t)b*3*NN + off;
  int coff = (tid & 31)*4;
  float a0=0.f, a1=0.f, a2=0.f, a3=0.f, ipn=0.f;
  int pk = (cnt > 0) ? eb[0] : 0;
  if (useb){
    const unsigned short* bufs16[4] = {sc0, sh0, sc1, sh1};
    const unsigned short* sb = bufs16[tid >> 5];
    for (int e = 0; e < cnt; e++){
      int pkn = (e+1 < cnt) ? eb[e+1] : 0;   // prefetch next edge
      int n = pk & 2047, et = pk >> 11;
      float w = wbuf[et*BN + (b<<11) + n];
      uint2 raw = *(const uint2*)(sb + ((size_t)(b<<11) + n)*128 + coff);
      ipn += w;
      a0 += w * b2f(raw.x & 0xffffu);
      a1 += w * b2f(raw.x >> 16);
      a2 += w * b2f(raw.y & 0xffffu);
      a3 += w * b2f(raw.y >> 16);
      pk = pkn;
    }
  } else {
    const float* sb = bufs[tid >> 5];
    for (int e = 0; e < cnt; e++){
      int pkn = (e+1 < cnt) ? eb[e+1] : 0;
      int n = pk & 2047, et = pk >> 11;
      float w = wbuf[et*BN + (b<<11) + n];
      float4 sv = *(const float4*)(sb + ((size_t)(b<<11) + n)*128 + coff);
      ipn += w;
      a0 += w * sv.x;
      a1 += w * sv.y;
      a2 += w * sv.z;
      a3 += w * sv.w;
      pk = pkn;
    }
  }
  int c = tid*4;
  float inv = 1.0f / (ipn + 1e-7f);
  out[obase + c+0] = a0*inv;
  out[obase + c+1] = a1*inv;
  out[obase + c+2] = a2*inv;
  out[obase + c+3] = a3*inv;
  if (tid == 0) out[obase + 512] = ipn;
}

extern "C" void kernel_launch(void* const* d_in, const int* in_sizes, int n_in,
                              void* d_out, int out_size, void* d_ws, size_t ws_size,
                              hipStream_t stream){
  const float* ne  = (const float*)d_in[0];
  float* c0  = (float*)d_in[1];   // updated in place only in f32-fallback mode
  float* h0  = (float*)d_in[2];
  float* c1  = (float*)d_in[3];
  float* h1  = (float*)d_in[4];
  const float* ip  = (const float*)d_in[5];
  const float* Wi0 = (const float*)d_in[6];
  const float* Wh0 = (const float*)d_in[7];
  const float* b0  = (const float*)d_in[8];
  const float* Wi1 = (const float*)d_in[9];
  const float* Wh1 = (const float*)d_in[10];
  const float* b1  = (const float*)d_in[11];
  const float* Wr  = (const float*)d_in[12];
  const float* br  = (const float*)d_in[13];
  const float* Wb  = (const float*)d_in[14];
  const float* bb  = (const float*)d_in[15];
  const int* ti  = (const int*)d_in[16];
  const int* fi  = (const int*)d_in[17];
  const int* ri  = (const int*)d_in[18];
  const int* ei  = (const int*)d_in[19];
  const int* rni = (const int*)d_in[20];
  const int* sl  = (const int*)d_in[21];
  const int* cs  = (const int*)d_in[22];
  float* out = (float*)d_out;

  // --- ws layout ---
  uint8_t* ws = (uint8_t*)d_ws;
  unsigned short* Bsw0    = (unsigned short*)(ws + 0);         // 262144 B
  unsigned short* Bsw1    = (unsigned short*)(ws + 262144);    // 262144 B
  float*          wbuf    = (float*)(ws + 655360);             // 786432 B
  int*            counts  = (int*)(ws + 1441792);              // 262144 B
  int*            offsets = (int*)(ws + 1703936);              // 262144 B
  int*            cursor  = (int*)(ws + 1966080);              // 262144 B
  unsigned short* edges   = (unsigned short*)(ws + 2228224);   // 393216 B
  // bf16 state sink (masked contrib) — only if workspace is big enough
  const size_t SBASE = 2621440;                                // 16B aligned
  const size_t SB    = (size_t)BN * 128 * 2;                   // 16 MiB each
  int useb = (ws_size >= SBASE + 4*SB) ? 1 : 0;
  unsigned short* sc0 = (unsigned short*)(ws + SBASE + 0*SB);
  unsigned short* sh0 = (unsigned short*)(ws + SBASE + 1*SB);
  unsigned short* sc1 = (unsigned short*)(ws + SBASE + 2*SB);
  unsigned short* sh1 = (unsigned short*)(ws + SBASE + 3*SB);

  hipMemsetAsync(counts, 0, BN*sizeof(int), stream);

  kswz<<<512, 64, 0, stream>>>(Wi0, Wh0, Wi1, Wh1, Bsw0, Bsw1);

  // fused 2-layer LSTM (r2 schedule); skips done batches; masked contrib to
  // bf16 ws (or predicated f32 in-place fallback)
  klstm2<<<BN/ROWSB, 512, 0, stream>>>(ne, c0, h0, c1, h1,
                                       sc0, sh0, sc1, sh1,
                                       Bsw0, b0, Bsw1, b1,
                                       ei, rni, sl, cs, useb);

  // decisions + edge counting
  kdec<<<BN/4, 256, 0, stream>>>(c0, h0, c1, h1, sc0, sh0, sc1, sh1,
                                 Wr, br, Wb, bb, ip, ei, rni,
                                 ri, ti, fi, counts, wbuf, useb);

  kscan<<<BB, 256, 0, stream>>>(counts, offsets, cursor);
  kfill<<<BN/256, 256, 0, stream>>>(ri, ti, fi, offsets, cursor, edges);

  kagg<<<BN, 128, 0, stream>>>(c0, h0, c1, h1, sc0, sh0, sc1, sh1,
                               ip, wbuf, edges, counts, offsets,
                               sl, cs, out, useb);
}

// Round 8
// 425.309 us; speedup vs baseline: 1.5752x; 1.0379x over previous
//
#include <hip/hip_runtime.h>
#include <stdint.h>

#define BB 32
#define NN 2048
#define HH 128
#define BN (BB*NN)

typedef short v8s __attribute__((ext_vector_type(8)));
typedef float v4f __attribute__((ext_vector_type(4)));

__device__ __forceinline__ unsigned short f2b(float f){
  union { float f; unsigned int i; } v; v.f = f;
  unsigned int x = v.i;
  unsigned int r = x + 0x7FFFu + ((x >> 16) & 1u);   // RNE f32 -> bf16
  return (unsigned short)(r >> 16);
}
__device__ __forceinline__ unsigned int pk2(float a, float b){
  return (unsigned int)f2b(a) | ((unsigned int)f2b(b) << 16);
}
__device__ __forceinline__ float b2f(unsigned int s){
  union { unsigned int i; float f; } v; v.i = s << 16; return v.f;
}
__device__ __forceinline__ float frcp(float x){ return __builtin_amdgcn_rcpf(x); }
// fast sigmoid / tanh: v_exp + v_rcp, ~1e-6 rel err (<< bf16 gate noise)
__device__ __forceinline__ float fsigm(float x){ return frcp(1.0f + __expf(-x)); }
__device__ __forceinline__ float ftanh(float x){ return 1.0f - 2.0f*frcp(1.0f + __expf(2.0f*x)); }

// ---------------- pre-swizzle B = [Wi;Wh] (f32) into bf16 MFMA fragment order
__global__ void kswz(const float* __restrict__ Wi0, const float* __restrict__ Wh0,
                     const float* __restrict__ Wi1, const float* __restrict__ Wh1,
                     unsigned short* __restrict__ Bsw0, unsigned short* __restrict__ Bsw1){
  int bid = blockIdx.x;            // 0..511
  int layer = bid >> 8;
  int kc = (bid >> 5) & 7;
  int ct = bid & 31;
  int lane = threadIdx.x;          // 0..63
  const float* Wi = layer ? Wi1 : Wi0;
  const float* Wh = layer ? Wh1 : Wh0;
  unsigned short* dst = layer ? Bsw1 : Bsw0;
  int col = ct*16 + (lane & 15);
  int kbase = kc*32 + (lane >> 4)*8;
  size_t o = ((size_t)(kc*32 + ct)*64 + (size_t)lane)*8;
  #pragma unroll
  for (int j = 0; j < 8; j++){
    int k = kbase + j;
    dst[o + j] = f2b((k < 128) ? Wi[k*512 + col] : Wh[(k-128)*512 + col]);
  }
}

// ---------------- fused 2-layer LSTM (r2 schedule; bf16 state sink) ---------
// Block: 32 rows, 512 threads (8 waves). Wave w owns channels w*16..w*16+15 of
// every gate (acc 32 regs/thread). NOTHING extra stays live across a GEMM
// (rounds 4-6 lesson: spills). Stores: if useb, masked contrib states go to
// bf16 ws arrays ONLY (f32 state buffers untouched -> done-path reads old);
// else f32 in-place with predicated-off special rows (r5 behavior).
#define ROWSB 32
#define PA 264   // ushorts/row of A tile: 256 + 8 pad
#define PH 136   // ushorts/row of H tiles: 128 + 8 pad

__global__ __launch_bounds__(512, 4) void klstm2(
    const float* __restrict__ ne,
    float* __restrict__ c0, float* __restrict__ h0,
    float* __restrict__ c1, float* __restrict__ h1,
    unsigned short* __restrict__ sc0, unsigned short* __restrict__ sh0,
    unsigned short* __restrict__ sc1, unsigned short* __restrict__ sh1,
    const unsigned short* __restrict__ Bsw0, const float* __restrict__ b0,
    const unsigned short* __restrict__ Bsw1, const float* __restrict__ b1,
    const int* __restrict__ exit_idx, const int* __restrict__ raise_idx,
    const int* __restrict__ step_limits, const int* __restrict__ cur_step,
    int useb)
{
  __shared__ unsigned short ldsA[ROWSB*PA];   // [ne | h0_old] bf16
  __shared__ unsigned short ldsH[ROWSB*PH];   // h1_old bf16
  __shared__ unsigned short ldsG[ROWSB*PH];   // h0_new bf16

  int rowbase = blockIdx.x * ROWSB;           // 32 rows, never crosses a batch
  int b = rowbase >> 11;
  if (cur_step[0] >= step_limits[b]) return;  // done batch: keep old states

  int tid = threadIdx.x;
  int wid = tid >> 6, lane = tid & 63;
  int quad = lane >> 4, l16 = lane & 15;
  int ch = wid*16 + l16;            // channel within each gate (0..127)
  int e_row = exit_idx[b], r_row = raise_idx[b];   // NODE indices (0..2047)

  // ---- stage A0 = bf16([ne | h0_old]) : 4 float4 per thread ----
  #pragma unroll
  for (int p = 0; p < 4; p++){
    int idx = p*512 + tid;
    int row = idx >> 6, chunk = idx & 63;     // chunk = float4 index (0..63)
    size_t g = (size_t)(rowbase + row)*128 + (chunk & 31)*4;
    float4 v = (chunk < 32) ? *(const float4*)(ne + g) : *(const float4*)(h0 + g);
    uint2 w; w.x = pk2(v.x, v.y); w.y = pk2(v.z, v.w);
    *(uint2*)&ldsA[row*PA + chunk*4] = w;
  }
  __syncthreads();

  // ---- prefetch c0 rows + layer-0 biases (independent of LDS; hidden by GEMM0)
  float cpre[8], bias[4];
  #pragma unroll
  for (int rt = 0; rt < 2; rt++)
    #pragma unroll
    for (int r = 0; r < 4; r++)
      cpre[rt*4+r] = c0[((size_t)rowbase + rt*16 + quad*4 + r)*128 + ch];
  #pragma unroll
  for (int g = 0; g < 4; g++) bias[g] = b0[g*128 + ch];

  // ---- stage H1 = bf16(h1_old) during GEMM0's shadow (consumed after b2) ----
  #pragma unroll
  for (int p = 0; p < 2; p++){
    int idx = p*512 + tid;
    int row = idx >> 5, chunk = idx & 31;
    float4 v = *(const float4*)(h1 + (size_t)(rowbase + row)*128 + chunk*4);
    uint2 w; w.x = pk2(v.x, v.y); w.y = pk2(v.z, v.w);
    *(uint2*)&ldsH[row*PH + chunk*4] = w;
  }

  // ================= layer 0: gates = [ne|h0_old] @ B0 =================
  const v8s* Bv0 = (const v8s*)Bsw0;
  v4f acc[2][4] = {};
  v8s bc[4], bn[4];
  #pragma unroll
  for (int g = 0; g < 4; g++) bc[g] = Bv0[(size_t)(g*8 + wid)*64 + lane];
  #pragma unroll
  for (int kc = 0; kc < 8; kc++){
    if (kc < 7){
      #pragma unroll
      for (int g = 0; g < 4; g++) bn[g] = Bv0[(size_t)((kc+1)*32 + g*8 + wid)*64 + lane];
    }
    v8s a0 = *(const v8s*)&ldsA[(0*16 + l16)*PA + kc*32 + quad*8];
    v8s a1 = *(const v8s*)&ldsA[(1*16 + l16)*PA + kc*32 + quad*8];
    #pragma unroll
    for (int g = 0; g < 4; g++){
      acc[0][g] = __builtin_amdgcn_mfma_f32_16x16x32_bf16(a0, bc[g], acc[0][g], 0,0,0);
      acc[1][g] = __builtin_amdgcn_mfma_f32_16x16x32_bf16(a1, bc[g], acc[1][g], 0,0,0);
    }
    #pragma unroll
    for (int g = 0; g < 4; g++) bc[g] = bn[g];
  }

  // ---- epilogue 0: LSTM update; h0_new -> ldsG; state -> bf16 ws or f32 ----
  #pragma unroll
  for (int rt = 0; rt < 2; rt++){
    #pragma unroll
    for (int r = 0; r < 4; r++){
      int k = rt*4 + r;
      int lrow = rt*16 + quad*4 + r;
      int grow = rowbase + lrow;
      int node = grow & 2047;
      bool special = (node == e_row) || (node == r_row);
      float iv = acc[rt][0][r] + bias[0];
      float fv = acc[rt][1][r] + bias[1];
      float gv = acc[rt][2][r] + bias[2];
      float ov = acc[rt][3][r] + bias[3];
      float cn = fsigm(fv)*cpre[k] + fsigm(iv)*ftanh(gv);
      float hn = fsigm(ov)*ftanh(cn);
      if (useb){
        // masked contrib in bf16: special rows hold OLD state
        sc0[(size_t)grow*128 + ch] = special ? f2b(cpre[k]) : f2b(cn);
        sh0[(size_t)grow*128 + ch] = special ? ldsA[lrow*PA + 128 + ch] : f2b(hn);
      } else if (!special){
        c0[(size_t)grow*128 + ch] = cn;
        h0[(size_t)grow*128 + ch] = hn;
      }
      ldsG[lrow*PH + ch] = f2b(hn);   // layer-1 A operand (UNMASKED h0n, per ref)
    }
  }

  // ---- prefetch c1 rows + layer-1 bias + first B1 frags (pre-barrier) ----
  #pragma unroll
  for (int rt = 0; rt < 2; rt++)
    #pragma unroll
    for (int r = 0; r < 4; r++)
      cpre[rt*4+r] = c1[((size_t)rowbase + rt*16 + quad*4 + r)*128 + ch];
  #pragma unroll
  for (int g = 0; g < 4; g++) bias[g] = b1[g*128 + ch];
  const v8s* Bv1 = (const v8s*)Bsw1;
  #pragma unroll
  for (int g = 0; g < 4; g++) bc[g] = Bv1[(size_t)(g*8 + wid)*64 + lane];

  __syncthreads();   // h0_new + h1_old LDS tiles complete

  // ================= layer 1: gates = [h0_new | h1_old] @ B1 =================
  #pragma unroll
  for (int rt = 0; rt < 2; rt++)
    #pragma unroll
    for (int g = 0; g < 4; g++)
      acc[rt][g] = (v4f){0.f, 0.f, 0.f, 0.f};
  #pragma unroll
  for (int kc = 0; kc < 8; kc++){
    if (kc < 7){
      #pragma unroll
      for (int g = 0; g < 4; g++) bn[g] = Bv1[(size_t)((kc+1)*32 + g*8 + wid)*64 + lane];
    }
    v8s a0, a1;
    if (kc < 4){
      a0 = *(const v8s*)&ldsG[(0*16 + l16)*PH + kc*32 + quad*8];
      a1 = *(const v8s*)&ldsG[(1*16 + l16)*PH + kc*32 + quad*8];
    } else {
      a0 = *(const v8s*)&ldsH[(0*16 + l16)*PH + (kc-4)*32 + quad*8];
      a1 = *(const v8s*)&ldsH[(1*16 + l16)*PH + (kc-4)*32 + quad*8];
    }
    #pragma unroll
    for (int g = 0; g < 4; g++){
      acc[0][g] = __builtin_amdgcn_mfma_f32_16x16x32_bf16(a0, bc[g], acc[0][g], 0,0,0);
      acc[1][g] = __builtin_amdgcn_mfma_f32_16x16x32_bf16(a1, bc[g], acc[1][g], 0,0,0);
    }
    #pragma unroll
    for (int g = 0; g < 4; g++) bc[g] = bn[g];
  }

  // ---- epilogue 1 ----
  #pragma unroll
  for (int rt = 0; rt < 2; rt++){
    #pragma unroll
    for (int r = 0; r < 4; r++){
      int k = rt*4 + r;
      int lrow = rt*16 + quad*4 + r;
      int grow = rowbase + lrow;
      int node = grow & 2047;
      bool special = (node == e_row) || (node == r_row);
      float iv = acc[rt][0][r] + bias[0];
      float fv = acc[rt][1][r] + bias[1];
      float gv = acc[rt][2][r] + bias[2];
      float ov = acc[rt][3][r] + bias[3];
      float cn = fsigm(fv)*cpre[k] + fsigm(iv)*ftanh(gv);
      float hn = fsigm(ov)*ftanh(cn);
      if (useb){
        sc1[(size_t)grow*128 + ch] = special ? f2b(cpre[k]) : f2b(cn);
        sh1[(size_t)grow*128 + ch] = special ? ldsH[lrow*PH + ch] : f2b(hn);
      } else if (!special){
        c1[(size_t)grow*128 + ch] = cn;
        h1[(size_t)grow*128 + ch] = hn;
      }
    }
  }
}

// ---------------- decisions: softmax(hs @ W) -> edge weights wr/wt/wf -------
__global__ __launch_bounds__(256) void kdec(
    const float* __restrict__ c0, const float* __restrict__ h0,
    const float* __restrict__ c1, const float* __restrict__ h1,
    const unsigned short* __restrict__ sc0, const unsigned short* __restrict__ sh0,
    const unsigned short* __restrict__ sc1, const unsigned short* __restrict__ sh1,
    const float* __restrict__ Wr, const float* __restrict__ br,
    const float* __restrict__ Wb, const float* __restrict__ bb,
    const float* __restrict__ ip,
    const int* __restrict__ exit_idx, const int* __restrict__ raise_idx,
    float* __restrict__ wbuf, int useb)
{
  int tid = threadIdx.x;
  int wid = tid >> 6, lane = tid & 63;
  int gid = blockIdx.x*4 + wid;          // node id
  int b = gid >> 11, n = gid & 2047;

  float hv[8];
  if (useb){
    const unsigned short* bufs16[4] = {sc0, sh0, sc1, sh1};
    const unsigned short* hb = bufs16[lane >> 4] + (size_t)gid*128 + (lane & 15)*8;
    uint4 raw = *(const uint4*)hb;        // 8 bf16
    hv[0] = b2f(raw.x & 0xffffu); hv[1] = b2f(raw.x >> 16);
    hv[2] = b2f(raw.y & 0xffffu); hv[3] = b2f(raw.y >> 16);
    hv[4] = b2f(raw.z & 0xffffu); hv[5] = b2f(raw.z >> 16);
    hv[6] = b2f(raw.w & 0xffffu); hv[7] = b2f(raw.w >> 16);
  } else {
    const float* bufs[4] = {c0, h0, c1, h1};
    const float* hb = bufs[lane >> 4] + (size_t)gid*128 + (lane & 15)*8;
    float4 hv0 = *(const float4*)hb;
    float4 hv1 = *(const float4*)(hb + 4);
    hv[0]=hv0.x; hv[1]=hv0.y; hv[2]=hv0.z; hv[3]=hv0.w;
    hv[4]=hv1.x; hv[5]=hv1.y; hv[6]=hv1.z; hv[7]=hv1.w;
  }
  const float* wrp = Wr + lane*16;
  const float* wbp = Wb + lane*16;
  float r0=0.f, r1=0.f, q0=0.f, q1=0.f;
  #pragma unroll
  for (int j = 0; j < 8; j++){
    float h = hv[j];
    r0 += h * wrp[j*2];  r1 += h * wrp[j*2+1];
    q0 += h * wbp[j*2];  q1 += h * wbp[j*2+1];
  }
  #pragma unroll
  for (int off = 32; off > 0; off >>= 1){
    r0 += __shfl_xor(r0, off, 64);
    r1 += __shfl_xor(r1, off, 64);
    q0 += __shfl_xor(q0, off, 64);
    q1 += __shfl_xor(q1, off, 64);
  }
  if (lane == 0){
    r0 += br[0]; r1 += br[1];
    q0 += bb[0]; q1 += bb[1];
    float pr, pn;
    if (n == exit_idx[b] || n == raise_idx[b]){ pr = 0.f; pn = 1.f; }
    else {
      float m = fmaxf(r0, r1);
      float e0 = __expf(r0 - m), e1 = __expf(r1 - m);
      pr = e0 / (e0 + e1); pn = e1 / (e0 + e1);
    }
    float m2 = fmaxf(q0, q1);
    float f0 = __expf(q0 - m2), f1 = __expf(q1 - m2);
    float pt = f0 / (f0 + f1), pf = f1 / (f0 + f1);
    float ipv = ip[gid];
    wbuf[0*BN + gid] = pr * ipv;
    wbuf[1*BN + gid] = pn * pt * ipv;
    wbuf[2*BN + gid] = pn * pf * ipv;
  }
}

// ---------------- CSR build, one block per batch, all in LDS ----------------
// replaces memset + kdec-atomics + kscan + kfill (3 launches + memset -> 1)
__global__ __launch_bounds__(1024) void kcsr(
    const int* __restrict__ ri, const int* __restrict__ ti,
    const int* __restrict__ fi,
    int* __restrict__ counts, int* __restrict__ offsets,
    unsigned short* __restrict__ edges)
{
  __shared__ int cnt[NN];     // 8 KB
  __shared__ int off[NN];     // 8 KB
  __shared__ int cur[NN];     // 8 KB
  __shared__ int wpart[16];

  int b = blockIdx.x, tid = threadIdx.x;
  const int* rp = ri + b*NN;
  const int* tp = ti + b*NN;
  const int* fp = fi + b*NN;

  #pragma unroll
  for (int p = 0; p < 2; p++){ cnt[p*1024 + tid] = 0; cur[p*1024 + tid] = 0; }
  __syncthreads();

  int rv[2], tv[2], fv[2];
  #pragma unroll
  for (int p = 0; p < 2; p++){
    int n = p*1024 + tid;
    rv[p] = rp[n]; tv[p] = tp[n]; fv[p] = fp[n];
    atomicAdd(&cnt[rv[p]], 1);
    atomicAdd(&cnt[tv[p]], 1);
    atomicAdd(&cnt[fv[p]], 1);
  }
  __syncthreads();

  // exclusive scan over 2048 counts: thread owns pair (2tid, 2tid+1)
  int c0 = cnt[2*tid], c1 = cnt[2*tid+1];
  int s = c0 + c1;
  int lane = tid & 63, wv = tid >> 6;
  int inc = s;
  #pragma unroll
  for (int d = 1; d < 64; d <<= 1){
    int t = __shfl_up(inc, d, 64);
    if (lane >= d) inc += t;
  }
  if (lane == 63) wpart[wv] = inc;
  __syncthreads();
  if (tid == 0){
    int run = 0;
    #pragma unroll
    for (int w = 0; w < 16; w++){ int t = wpart[w]; wpart[w] = run; run += t; }
  }
  __syncthreads();
  int excl = wpart[wv] + inc - s;
  off[2*tid]   = excl;
  off[2*tid+1] = excl + c0;
  offsets[b*NN + 2*tid]   = excl;
  offsets[b*NN + 2*tid+1] = excl + c0;
  counts[b*NN + 2*tid]   = c0;
  counts[b*NN + 2*tid+1] = c1;
  __syncthreads();

  size_t ebase = (size_t)b*3*NN;
  #pragma unroll
  for (int p = 0; p < 2; p++){
    int n = p*1024 + tid;
    int t0 = rv[p]; int p0 = atomicAdd(&cur[t0], 1);
    edges[ebase + off[t0] + p0] = (unsigned short)n;
    int t1 = tv[p]; int p1 = atomicAdd(&cur[t1], 1);
    edges[ebase + off[t1] + p1] = (unsigned short)(n | (1<<11));
    int t2 = fv[p]; int p2 = atomicAdd(&cur[t2], 1);
    edges[ebase + off[t2] + p2] = (unsigned short)(n | (2<<11));
  }
}

// ---------------- gather + normalize + output (4 nodes / block) -------------
__global__ __launch_bounds__(512) void kagg(
    const float* __restrict__ c0, const float* __restrict__ h0,
    const float* __restrict__ c1, const float* __restrict__ h1,
    const unsigned short* __restrict__ sc0, const unsigned short* __restrict__ sh0,
    const unsigned short* __restrict__ sc1, const unsigned short* __restrict__ sh1,
    const float* __restrict__ ip,
    const float* __restrict__ wbuf, const unsigned short* __restrict__ edges,
    const int* __restrict__ counts, const int* __restrict__ offsets,
    const int* __restrict__ step_limits, const int* __restrict__ cur_step,
    float* __restrict__ out, int useb)
{
  int tid0 = threadIdx.x;
  int sub = tid0 >> 7;             // node within block (0..3)
  int tid = tid0 & 127;            // 0..127, channels tid*4..tid*4+3
  int gid = blockIdx.x*4 + sub;    // b*N + j
  int b = gid >> 11;
  size_t obase = (size_t)gid*513;
  const float* bufs[4] = {c0, h0, c1, h1};

  if (cur_step[0] >= step_limits[b]){       // done: copy old state + old ip
    int c = tid*4;
    const float* s = bufs[c >> 7];
    size_t rb = (size_t)gid*128 + (c & 127);
    out[obase + c+0] = s[rb+0];
    out[obase + c+1] = s[rb+1];
    out[obase + c+2] = s[rb+2];
    out[obase + c+3] = s[rb+3];
    if (tid == 0) out[obase + 512] = ip[gid];
    return;
  }

  int cnt = counts[gid], off = offsets[gid];
  const unsigned short* eb = edges + (size_t)b*3*NN + off;
  int coff = (tid & 31)*4;
  float a0=0.f, a1=0.f, a2=0.f, a3=0.f, ipn=0.f;
  int pk = (cnt > 0) ? eb[0] : 0;
  if (useb){
    const unsigned short* bufs16[4] = {sc0, sh0, sc1, sh1};
    const unsigned short* sb = bufs16[tid >> 5];
    for (int e = 0; e < cnt; e++){
      int pkn = (e+1 < cnt) ? eb[e+1] : 0;   // prefetch next edge
      int n = pk & 2047, et = pk >> 11;
      float w = wbuf[et*BN + (b<<11) + n];
      uint2 raw = *(const uint2*)(sb + ((size_t)(b<<11) + n)*128 + coff);
      ipn += w;
      a0 += w * b2f(raw.x & 0xffffu);
      a1 += w * b2f(raw.x >> 16);
      a2 += w * b2f(raw.y & 0xffffu);
      a3 += w * b2f(raw.y >> 16);
      pk = pkn;
    }
  } else {
    const float* sb = bufs[tid >> 5];
    for (int e = 0; e < cnt; e++){
      int pkn = (e+1 < cnt) ? eb[e+1] : 0;
      int n = pk & 2047, et = pk >> 11;
      float w = wbuf[et*BN + (b<<11) + n];
      float4 sv = *(const float4*)(sb + ((size_t)(b<<11) + n)*128 + coff);
      ipn += w;
      a0 += w * sv.x;
      a1 += w * sv.y;
      a2 += w * sv.z;
      a3 += w * sv.w;
      pk = pkn;
    }
  }
  int c = tid*4;
  float inv = 1.0f / (ipn + 1e-7f);
  out[obase + c+0] = a0*inv;
  out[obase + c+1] = a1*inv;
  out[obase + c+2] = a2*inv;
  out[obase + c+3] = a3*inv;
  if (tid == 0) out[obase + 512] = ipn;
}

extern "C" void kernel_launch(void* const* d_in, const int* in_sizes, int n_in,
                              void* d_out, int out_size, void* d_ws, size_t ws_size,
                              hipStream_t stream){
  const float* ne  = (const float*)d_in[0];
  float* c0  = (float*)d_in[1];   // updated in place only in f32-fallback mode
  float* h0  = (float*)d_in[2];
  float* c1  = (float*)d_in[3];
  float* h1  = (float*)d_in[4];
  const float* ip  = (const float*)d_in[5];
  const float* Wi0 = (const float*)d_in[6];
  const float* Wh0 = (const float*)d_in[7];
  const float* b0  = (const float*)d_in[8];
  const float* Wi1 = (const float*)d_in[9];
  const float* Wh1 = (const float*)d_in[10];
  const float* b1  = (const float*)d_in[11];
  const float* Wr  = (const float*)d_in[12];
  const float* br  = (const float*)d_in[13];
  const float* Wb  = (const float*)d_in[14];
  const float* bb  = (const float*)d_in[15];
  const int* ti  = (const int*)d_in[16];
  const int* fi  = (const int*)d_in[17];
  const int* ri  = (const int*)d_in[18];
  const int* ei  = (const int*)d_in[19];
  const int* rni = (const int*)d_in[20];
  const int* sl  = (const int*)d_in[21];
  const int* cs  = (const int*)d_in[22];
  float* out = (float*)d_out;

  // --- ws layout ---
  uint8_t* ws = (uint8_t*)d_ws;
  unsigned short* Bsw0    = (unsigned short*)(ws + 0);         // 262144 B
  unsigned short* Bsw1    = (unsigned short*)(ws + 262144);    // 262144 B
  float*          wbuf    = (float*)(ws + 655360);             // 786432 B
  int*            counts  = (int*)(ws + 1441792);              // 262144 B
  int*            offsets = (int*)(ws + 1703936);              // 262144 B
  unsigned short* edges   = (unsigned short*)(ws + 2228224);   // 393216 B
  // bf16 state sink (masked contrib) — only if workspace is big enough
  const size_t SBASE = 2621440;                                // 16B aligned
  const size_t SB    = (size_t)BN * 128 * 2;                   // 16 MiB each
  int useb = (ws_size >= SBASE + 4*SB) ? 1 : 0;
  unsigned short* sc0 = (unsigned short*)(ws + SBASE + 0*SB);
  unsigned short* sh0 = (unsigned short*)(ws + SBASE + 1*SB);
  unsigned short* sc1 = (unsigned short*)(ws + SBASE + 2*SB);
  unsigned short* sh1 = (unsigned short*)(ws + SBASE + 3*SB);

  kswz<<<512, 64, 0, stream>>>(Wi0, Wh0, Wi1, Wh1, Bsw0, Bsw1);

  // CSR build: depends only on edge-index inputs
  kcsr<<<BB, 1024, 0, stream>>>(ri, ti, fi, counts, offsets, edges);

  // fused 2-layer LSTM (r2 schedule); skips done batches; masked contrib to
  // bf16 ws (or predicated f32 in-place fallback)
  klstm2<<<BN/ROWSB, 512, 0, stream>>>(ne, c0, h0, c1, h1,
                                       sc0, sh0, sc1, sh1,
                                       Bsw0, b0, Bsw1, b1,
                                       ei, rni, sl, cs, useb);

  // decisions
  kdec<<<BN/4, 256, 0, stream>>>(c0, h0, c1, h1, sc0, sh0, sc1, sh1,
                                 Wr, br, Wb, bb, ip, ei, rni, wbuf, useb);

  kagg<<<BN/4, 512, 0, stream>>>(c0, h0, c1, h1, sc0, sh0, sc1, sh1,
                                 ip, wbuf, edges, counts, offsets,
                                 sl, cs, out, useb);
}

// Round 9
// 424.507 us; speedup vs baseline: 1.5782x; 1.0019x over previous
//
#include <hip/hip_runtime.h>
#include <stdint.h>

#define BB 32
#define NN 2048
#define HH 128
#define BN (BB*NN)

typedef short v8s __attribute__((ext_vector_type(8)));
typedef float v4f __attribute__((ext_vector_type(4)));

__device__ __forceinline__ unsigned short f2b(float f){
  union { float f; unsigned int i; } v; v.f = f;
  unsigned int x = v.i;
  unsigned int r = x + 0x7FFFu + ((x >> 16) & 1u);   // RNE f32 -> bf16
  return (unsigned short)(r >> 16);
}
__device__ __forceinline__ unsigned int pk2(float a, float b){
  return (unsigned int)f2b(a) | ((unsigned int)f2b(b) << 16);
}
__device__ __forceinline__ float b2f(unsigned int s){
  union { unsigned int i; float f; } v; v.i = s << 16; return v.f;
}
__device__ __forceinline__ float frcp(float x){ return __builtin_amdgcn_rcpf(x); }
// fast sigmoid / tanh: v_exp + v_rcp, ~1e-6 rel err (<< bf16 gate noise)
__device__ __forceinline__ float fsigm(float x){ return frcp(1.0f + __expf(-x)); }
__device__ __forceinline__ float ftanh(float x){ return 1.0f - 2.0f*frcp(1.0f + __expf(2.0f*x)); }

// ---------------- prep: CSR build (blocks 0..31) + B pre-swizzle (32..63) ---
// CSR: one block per batch, counts/scan/fill entirely in LDS.
// Swizzle: Bsw[((kc*32+ct)*64+lane)*8+j] = bf16(Bcat[kc*32+(lane>>4)*8+j][ct*16+(lane&15)])
__global__ __launch_bounds__(1024) void kprep(
    const int* __restrict__ ri, const int* __restrict__ ti,
    const int* __restrict__ fi,
    int* __restrict__ counts, int* __restrict__ offsets,
    unsigned short* __restrict__ edges,
    const float* __restrict__ Wi0, const float* __restrict__ Wh0,
    const float* __restrict__ Wi1, const float* __restrict__ Wh1,
    unsigned short* __restrict__ Bsw0, unsigned short* __restrict__ Bsw1)
{
  __shared__ int cnt[NN];     // 8 KB
  __shared__ int off[NN];     // 8 KB
  __shared__ int cur[NN];     // 8 KB
  __shared__ int wpart[16];

  int tid = threadIdx.x;

  if (blockIdx.x >= 32){
    // ---------------- B pre-swizzle ----------------
    int idx = (blockIdx.x - 32)*1024 + tid;   // 0..32767
    int bid = idx >> 6;                       // 0..511
    int lane = idx & 63;
    int layer = bid >> 8;
    int kc = (bid >> 5) & 7;
    int ct = bid & 31;
    const float* Wi = layer ? Wi1 : Wi0;
    const float* Wh = layer ? Wh1 : Wh0;
    unsigned short* dst = layer ? Bsw1 : Bsw0;
    int col = ct*16 + (lane & 15);
    int kbase = kc*32 + (lane >> 4)*8;
    size_t o = ((size_t)(kc*32 + ct)*64 + (size_t)lane)*8;
    #pragma unroll
    for (int j = 0; j < 8; j++){
      int k = kbase + j;
      dst[o + j] = f2b((k < 128) ? Wi[k*512 + col] : Wh[(k-128)*512 + col]);
    }
    return;
  }

  // ---------------- CSR build for batch b ----------------
  int b = blockIdx.x;
  const int* rp = ri + b*NN;
  const int* tp = ti + b*NN;
  const int* fp = fi + b*NN;

  #pragma unroll
  for (int p = 0; p < 2; p++){ cnt[p*1024 + tid] = 0; cur[p*1024 + tid] = 0; }
  __syncthreads();

  int rv[2], tv[2], fv[2];
  #pragma unroll
  for (int p = 0; p < 2; p++){
    int n = p*1024 + tid;
    rv[p] = rp[n]; tv[p] = tp[n]; fv[p] = fp[n];
    atomicAdd(&cnt[rv[p]], 1);
    atomicAdd(&cnt[tv[p]], 1);
    atomicAdd(&cnt[fv[p]], 1);
  }
  __syncthreads();

  // exclusive scan over 2048 counts: thread owns pair (2tid, 2tid+1)
  int c0 = cnt[2*tid], c1 = cnt[2*tid+1];
  int s = c0 + c1;
  int lane = tid & 63, wv = tid >> 6;
  int inc = s;
  #pragma unroll
  for (int d = 1; d < 64; d <<= 1){
    int t = __shfl_up(inc, d, 64);
    if (lane >= d) inc += t;
  }
  if (lane == 63) wpart[wv] = inc;
  __syncthreads();
  if (tid == 0){
    int run = 0;
    #pragma unroll
    for (int w = 0; w < 16; w++){ int t = wpart[w]; wpart[w] = run; run += t; }
  }
  __syncthreads();
  int excl = wpart[wv] + inc - s;
  off[2*tid]   = excl;
  off[2*tid+1] = excl + c0;
  offsets[b*NN + 2*tid]   = excl;
  offsets[b*NN + 2*tid+1] = excl + c0;
  counts[b*NN + 2*tid]   = c0;
  counts[b*NN + 2*tid+1] = c1;
  __syncthreads();

  size_t ebase = (size_t)b*3*NN;
  #pragma unroll
  for (int p = 0; p < 2; p++){
    int n = p*1024 + tid;
    int t0 = rv[p]; int p0 = atomicAdd(&cur[t0], 1);
    edges[ebase + off[t0] + p0] = (unsigned short)n;
    int t1 = tv[p]; int p1 = atomicAdd(&cur[t1], 1);
    edges[ebase + off[t1] + p1] = (unsigned short)(n | (1<<11));
    int t2 = fv[p]; int p2 = atomicAdd(&cur[t2], 1);
    edges[ebase + off[t2] + p2] = (unsigned short)(n | (2<<11));
  }
}

// ---------------- fused 2-layer LSTM (r2 schedule; bf16 state sink) ---------
// Block: 32 rows, 512 threads (8 waves). Wave w owns channels w*16..w*16+15 of
// every gate (acc 32 regs/thread). NOTHING extra stays live across a GEMM
// (rounds 4-6 lesson: spills). Stores: if useb, masked contrib states go to
// bf16 ws arrays ONLY (f32 state buffers untouched -> done-path reads old);
// else f32 in-place with predicated-off special rows (r5 behavior).
#define ROWSB 32
#define PA 264   // ushorts/row of A tile: 256 + 8 pad
#define PH 136   // ushorts/row of H tiles: 128 + 8 pad

__global__ __launch_bounds__(512, 4) void klstm2(
    const float* __restrict__ ne,
    float* __restrict__ c0, float* __restrict__ h0,
    float* __restrict__ c1, float* __restrict__ h1,
    unsigned short* __restrict__ sc0, unsigned short* __restrict__ sh0,
    unsigned short* __restrict__ sc1, unsigned short* __restrict__ sh1,
    const unsigned short* __restrict__ Bsw0, const float* __restrict__ b0,
    const unsigned short* __restrict__ Bsw1, const float* __restrict__ b1,
    const int* __restrict__ exit_idx, const int* __restrict__ raise_idx,
    const int* __restrict__ step_limits, const int* __restrict__ cur_step,
    int useb)
{
  __shared__ unsigned short ldsA[ROWSB*PA];   // [ne | h0_old] bf16
  __shared__ unsigned short ldsH[ROWSB*PH];   // h1_old bf16
  __shared__ unsigned short ldsG[ROWSB*PH];   // h0_new bf16

  int rowbase = blockIdx.x * ROWSB;           // 32 rows, never crosses a batch
  int b = rowbase >> 11;
  if (cur_step[0] >= step_limits[b]) return;  // done batch: keep old states

  int tid = threadIdx.x;
  int wid = tid >> 6, lane = tid & 63;
  int quad = lane >> 4, l16 = lane & 15;
  int ch = wid*16 + l16;            // channel within each gate (0..127)
  int e_row = exit_idx[b], r_row = raise_idx[b];   // NODE indices (0..2047)

  // ---- stage A0 = bf16([ne | h0_old]) : 4 float4 per thread ----
  #pragma unroll
  for (int p = 0; p < 4; p++){
    int idx = p*512 + tid;
    int row = idx >> 6, chunk = idx & 63;     // chunk = float4 index (0..63)
    size_t g = (size_t)(rowbase + row)*128 + (chunk & 31)*4;
    float4 v = (chunk < 32) ? *(const float4*)(ne + g) : *(const float4*)(h0 + g);
    uint2 w; w.x = pk2(v.x, v.y); w.y = pk2(v.z, v.w);
    *(uint2*)&ldsA[row*PA + chunk*4] = w;
  }
  __syncthreads();

  // ---- prefetch c0 rows + layer-0 biases (independent of LDS; hidden by GEMM0)
  float cpre[8], bias[4];
  #pragma unroll
  for (int rt = 0; rt < 2; rt++)
    #pragma unroll
    for (int r = 0; r < 4; r++)
      cpre[rt*4+r] = c0[((size_t)rowbase + rt*16 + quad*4 + r)*128 + ch];
  #pragma unroll
  for (int g = 0; g < 4; g++) bias[g] = b0[g*128 + ch];

  // ---- stage H1 = bf16(h1_old) during GEMM0's shadow (consumed after b2) ----
  #pragma unroll
  for (int p = 0; p < 2; p++){
    int idx = p*512 + tid;
    int row = idx >> 5, chunk = idx & 31;
    float4 v = *(const float4*)(h1 + (size_t)(rowbase + row)*128 + chunk*4);
    uint2 w; w.x = pk2(v.x, v.y); w.y = pk2(v.z, v.w);
    *(uint2*)&ldsH[row*PH + chunk*4] = w;
  }

  // ================= layer 0: gates = [ne|h0_old] @ B0 =================
  const v8s* Bv0 = (const v8s*)Bsw0;
  v4f acc[2][4] = {};
  v8s bc[4], bn[4];
  #pragma unroll
  for (int g = 0; g < 4; g++) bc[g] = Bv0[(size_t)(g*8 + wid)*64 + lane];
  #pragma unroll
  for (int kc = 0; kc < 8; kc++){
    if (kc < 7){
      #pragma unroll
      for (int g = 0; g < 4; g++) bn[g] = Bv0[(size_t)((kc+1)*32 + g*8 + wid)*64 + lane];
    }
    v8s a0 = *(const v8s*)&ldsA[(0*16 + l16)*PA + kc*32 + quad*8];
    v8s a1 = *(const v8s*)&ldsA[(1*16 + l16)*PA + kc*32 + quad*8];
    #pragma unroll
    for (int g = 0; g < 4; g++){
      acc[0][g] = __builtin_amdgcn_mfma_f32_16x16x32_bf16(a0, bc[g], acc[0][g], 0,0,0);
      acc[1][g] = __builtin_amdgcn_mfma_f32_16x16x32_bf16(a1, bc[g], acc[1][g], 0,0,0);
    }
    #pragma unroll
    for (int g = 0; g < 4; g++) bc[g] = bn[g];
  }

  // ---- epilogue 0: LSTM update; h0_new -> ldsG; state -> bf16 ws or f32 ----
  #pragma unroll
  for (int rt = 0; rt < 2; rt++){
    #pragma unroll
    for (int r = 0; r < 4; r++){
      int k = rt*4 + r;
      int lrow = rt*16 + quad*4 + r;
      int grow = rowbase + lrow;
      int node = grow & 2047;
      bool special = (node == e_row) || (node == r_row);
      float iv = acc[rt][0][r] + bias[0];
      float fv = acc[rt][1][r] + bias[1];
      float gv = acc[rt][2][r] + bias[2];
      float ov = acc[rt][3][r] + bias[3];
      float cn = fsigm(fv)*cpre[k] + fsigm(iv)*ftanh(gv);
      float hn = fsigm(ov)*ftanh(cn);
      if (useb){
        // masked contrib in bf16: special rows hold OLD state
        sc0[(size_t)grow*128 + ch] = special ? f2b(cpre[k]) : f2b(cn);
        sh0[(size_t)grow*128 + ch] = special ? ldsA[lrow*PA + 128 + ch] : f2b(hn);
      } else if (!special){
        c0[(size_t)grow*128 + ch] = cn;
        h0[(size_t)grow*128 + ch] = hn;
      }
      ldsG[lrow*PH + ch] = f2b(hn);   // layer-1 A operand (UNMASKED h0n, per ref)
    }
  }

  // ---- prefetch c1 rows + layer-1 bias + first B1 frags (pre-barrier) ----
  #pragma unroll
  for (int rt = 0; rt < 2; rt++)
    #pragma unroll
    for (int r = 0; r < 4; r++)
      cpre[rt*4+r] = c1[((size_t)rowbase + rt*16 + quad*4 + r)*128 + ch];
  #pragma unroll
  for (int g = 0; g < 4; g++) bias[g] = b1[g*128 + ch];
  const v8s* Bv1 = (const v8s*)Bsw1;
  #pragma unroll
  for (int g = 0; g < 4; g++) bc[g] = Bv1[(size_t)(g*8 + wid)*64 + lane];

  __syncthreads();   // h0_new + h1_old LDS tiles complete

  // ================= layer 1: gates = [h0_new | h1_old] @ B1 =================
  #pragma unroll
  for (int rt = 0; rt < 2; rt++)
    #pragma unroll
    for (int g = 0; g < 4; g++)
      acc[rt][g] = (v4f){0.f, 0.f, 0.f, 0.f};
  #pragma unroll
  for (int kc = 0; kc < 8; kc++){
    if (kc < 7){
      #pragma unroll
      for (int g = 0; g < 4; g++) bn[g] = Bv1[(size_t)((kc+1)*32 + g*8 + wid)*64 + lane];
    }
    v8s a0, a1;
    if (kc < 4){
      a0 = *(const v8s*)&ldsG[(0*16 + l16)*PH + kc*32 + quad*8];
      a1 = *(const v8s*)&ldsG[(1*16 + l16)*PH + kc*32 + quad*8];
    } else {
      a0 = *(const v8s*)&ldsH[(0*16 + l16)*PH + (kc-4)*32 + quad*8];
      a1 = *(const v8s*)&ldsH[(1*16 + l16)*PH + (kc-4)*32 + quad*8];
    }
    #pragma unroll
    for (int g = 0; g < 4; g++){
      acc[0][g] = __builtin_amdgcn_mfma_f32_16x16x32_bf16(a0, bc[g], acc[0][g], 0,0,0);
      acc[1][g] = __builtin_amdgcn_mfma_f32_16x16x32_bf16(a1, bc[g], acc[1][g], 0,0,0);
    }
    #pragma unroll
    for (int g = 0; g < 4; g++) bc[g] = bn[g];
  }

  // ---- epilogue 1 ----
  #pragma unroll
  for (int rt = 0; rt < 2; rt++){
    #pragma unroll
    for (int r = 0; r < 4; r++){
      int k = rt*4 + r;
      int lrow = rt*16 + quad*4 + r;
      int grow = rowbase + lrow;
      int node = grow & 2047;
      bool special = (node == e_row) || (node == r_row);
      float iv = acc[rt][0][r] + bias[0];
      float fv = acc[rt][1][r] + bias[1];
      float gv = acc[rt][2][r] + bias[2];
      float ov = acc[rt][3][r] + bias[3];
      float cn = fsigm(fv)*cpre[k] + fsigm(iv)*ftanh(gv);
      float hn = fsigm(ov)*ftanh(cn);
      if (useb){
        sc1[(size_t)grow*128 + ch] = special ? f2b(cpre[k]) : f2b(cn);
        sh1[(size_t)grow*128 + ch] = special ? ldsH[lrow*PH + ch] : f2b(hn);
      } else if (!special){
        c1[(size_t)grow*128 + ch] = cn;
        h1[(size_t)grow*128 + ch] = hn;
      }
    }
  }
}

// ---------------- decisions: softmax(hs @ W) -> edge weights wr/wt/wf -------
__global__ __launch_bounds__(256) void kdec(
    const float* __restrict__ c0, const float* __restrict__ h0,
    const float* __restrict__ c1, const float* __restrict__ h1,
    const unsigned short* __restrict__ sc0, const unsigned short* __restrict__ sh0,
    const unsigned short* __restrict__ sc1, const unsigned short* __restrict__ sh1,
    const float* __restrict__ Wr, const float* __restrict__ br,
    const float* __restrict__ Wb, const float* __restrict__ bb,
    const float* __restrict__ ip,
    const int* __restrict__ exit_idx, const int* __restrict__ raise_idx,
    float* __restrict__ wbuf, int useb)
{
  int tid = threadIdx.x;
  int wid = tid >> 6, lane = tid & 63;
  int gid = blockIdx.x*4 + wid;          // node id
  int b = gid >> 11, n = gid & 2047;

  float hv[8];
  if (useb){
    const unsigned short* bufs16[4] = {sc0, sh0, sc1, sh1};
    const unsigned short* hb = bufs16[lane >> 4] + (size_t)gid*128 + (lane & 15)*8;
    uint4 raw = *(const uint4*)hb;        // 8 bf16
    hv[0] = b2f(raw.x & 0xffffu); hv[1] = b2f(raw.x >> 16);
    hv[2] = b2f(raw.y & 0xffffu); hv[3] = b2f(raw.y >> 16);
    hv[4] = b2f(raw.z & 0xffffu); hv[5] = b2f(raw.z >> 16);
    hv[6] = b2f(raw.w & 0xffffu); hv[7] = b2f(raw.w >> 16);
  } else {
    const float* bufs[4] = {c0, h0, c1, h1};
    const float* hb = bufs[lane >> 4] + (size_t)gid*128 + (lane & 15)*8;
    float4 hv0 = *(const float4*)hb;
    float4 hv1 = *(const float4*)(hb + 4);
    hv[0]=hv0.x; hv[1]=hv0.y; hv[2]=hv0.z; hv[3]=hv0.w;
    hv[4]=hv1.x; hv[5]=hv1.y; hv[6]=hv1.z; hv[7]=hv1.w;
  }
  const float* wrp = Wr + lane*16;
  const float* wbp = Wb + lane*16;
  float r0=0.f, r1=0.f, q0=0.f, q1=0.f;
  #pragma unroll
  for (int j = 0; j < 8; j++){
    float h = hv[j];
    r0 += h * wrp[j*2];  r1 += h * wrp[j*2+1];
    q0 += h * wbp[j*2];  q1 += h * wbp[j*2+1];
  }
  #pragma unroll
  for (int off = 32; off > 0; off >>= 1){
    r0 += __shfl_xor(r0, off, 64);
    r1 += __shfl_xor(r1, off, 64);
    q0 += __shfl_xor(q0, off, 64);
    q1 += __shfl_xor(q1, off, 64);
  }
  if (lane == 0){
    r0 += br[0]; r1 += br[1];
    q0 += bb[0]; q1 += bb[1];
    float pr, pn;
    if (n == exit_idx[b] || n == raise_idx[b]){ pr = 0.f; pn = 1.f; }
    else {
      float m = fmaxf(r0, r1);
      float e0 = __expf(r0 - m), e1 = __expf(r1 - m);
      pr = e0 / (e0 + e1); pn = e1 / (e0 + e1);
    }
    float m2 = fmaxf(q0, q1);
    float f0 = __expf(q0 - m2), f1 = __expf(q1 - m2);
    float pt = f0 / (f0 + f1), pf = f1 / (f0 + f1);
    float ipv = ip[gid];
    wbuf[0*BN + gid] = pr * ipv;
    wbuf[1*BN + gid] = pn * pt * ipv;
    wbuf[2*BN + gid] = pn * pf * ipv;
  }
}

// ---------------- gather + normalize + output (4 nodes / block) -------------
// Phase 1: lanes fetch all (n,w) edge pairs in parallel; phase 2: shfl
// broadcast -> state-row gathers have NO inter-iteration memory dependency.
__global__ __launch_bounds__(512) void kagg(
    const float* __restrict__ c0, const float* __restrict__ h0,
    const float* __restrict__ c1, const float* __restrict__ h1,
    const unsigned short* __restrict__ sc0, const unsigned short* __restrict__ sh0,
    const unsigned short* __restrict__ sc1, const unsigned short* __restrict__ sh1,
    const float* __restrict__ ip,
    const float* __restrict__ wbuf, const unsigned short* __restrict__ edges,
    const int* __restrict__ counts, const int* __restrict__ offsets,
    const int* __restrict__ step_limits, const int* __restrict__ cur_step,
    float* __restrict__ out, int useb)
{
  int tid0 = threadIdx.x;
  int sub = tid0 >> 7;             // node within block (0..3)
  int tid = tid0 & 127;            // 0..127, channels tid*4..tid*4+3
  int gid = blockIdx.x*4 + sub;    // b*N + j
  int b = gid >> 11;
  size_t obase = (size_t)gid*513;
  const float* bufs[4] = {c0, h0, c1, h1};

  if (cur_step[0] >= step_limits[b]){       // done: copy old state + old ip
    int c = tid*4;
    const float* s = bufs[c >> 7];
    size_t rb = (size_t)gid*128 + (c & 127);
    out[obase + c+0] = s[rb+0];
    out[obase + c+1] = s[rb+1];
    out[obase + c+2] = s[rb+2];
    out[obase + c+3] = s[rb+3];
    if (tid == 0) out[obase + 512] = ip[gid];
    return;
  }

  int cnt = counts[gid], off = offsets[gid];
  const unsigned short* eb = edges + (size_t)b*3*NN + off;
  int lane = tid & 63;
  int coff = (tid & 31)*4;
  float a0=0.f, a1=0.f, a2=0.f, a3=0.f, ipn=0.f;

  if (useb){
    const unsigned short* bufs16[4] = {sc0, sh0, sc1, sh1};
    const unsigned short* sb = bufs16[tid >> 5];
    for (int base = 0; base < cnt; base += 64){
      int e = base + lane;
      int n_l = 0; float w_l = 0.f;
      if (e < cnt){
        int pk = eb[e];
        n_l = pk & 2047;
        w_l = wbuf[(pk >> 11)*BN + (b<<11) + n_l];
      }
      int m = min(cnt - base, 64);
      for (int j = 0; j < m; j++){
        int   n = __shfl(n_l, j, 64);
        float w = __shfl(w_l, j, 64);
        uint2 raw = *(const uint2*)(sb + ((size_t)(b<<11) + n)*128 + coff);
        ipn += w;
        a0 += w * b2f(raw.x & 0xffffu);
        a1 += w * b2f(raw.x >> 16);
        a2 += w * b2f(raw.y & 0xffffu);
        a3 += w * b2f(raw.y >> 16);
      }
    }
  } else {
    const float* sb = bufs[tid >> 5];
    for (int base = 0; base < cnt; base += 64){
      int e = base + lane;
      int n_l = 0; float w_l = 0.f;
      if (e < cnt){
        int pk = eb[e];
        n_l = pk & 2047;
        w_l = wbuf[(pk >> 11)*BN + (b<<11) + n_l];
      }
      int m = min(cnt - base, 64);
      for (int j = 0; j < m; j++){
        int   n = __shfl(n_l, j, 64);
        float w = __shfl(w_l, j, 64);
        float4 sv = *(const float4*)(sb + ((size_t)(b<<11) + n)*128 + coff);
        ipn += w;
        a0 += w * sv.x;
        a1 += w * sv.y;
        a2 += w * sv.z;
        a3 += w * sv.w;
      }
    }
  }
  int c = tid*4;
  float inv = 1.0f / (ipn + 1e-7f);
  out[obase + c+0] = a0*inv;
  out[obase + c+1] = a1*inv;
  out[obase + c+2] = a2*inv;
  out[obase + c+3] = a3*inv;
  if (tid == 0) out[obase + 512] = ipn;
}

extern "C" void kernel_launch(void* const* d_in, const int* in_sizes, int n_in,
                              void* d_out, int out_size, void* d_ws, size_t ws_size,
                              hipStream_t stream){
  const float* ne  = (const float*)d_in[0];
  float* c0  = (float*)d_in[1];   // updated in place only in f32-fallback mode
  float* h0  = (float*)d_in[2];
  float* c1  = (float*)d_in[3];
  float* h1  = (float*)d_in[4];
  const float* ip  = (const float*)d_in[5];
  const float* Wi0 = (const float*)d_in[6];
  const float* Wh0 = (const float*)d_in[7];
  const float* b0  = (const float*)d_in[8];
  const float* Wi1 = (const float*)d_in[9];
  const float* Wh1 = (const float*)d_in[10];
  const float* b1  = (const float*)d_in[11];
  const float* Wr  = (const float*)d_in[12];
  const float* br  = (const float*)d_in[13];
  const float* Wb  = (const float*)d_in[14];
  const float* bb  = (const float*)d_in[15];
  const int* ti  = (const int*)d_in[16];
  const int* fi  = (const int*)d_in[17];
  const int* ri  = (const int*)d_in[18];
  const int* ei  = (const int*)d_in[19];
  const int* rni = (const int*)d_in[20];
  const int* sl  = (const int*)d_in[21];
  const int* cs  = (const int*)d_in[22];
  float* out = (float*)d_out;

  // --- ws layout ---
  uint8_t* ws = (uint8_t*)d_ws;
  unsigned short* Bsw0    = (unsigned short*)(ws + 0);         // 262144 B
  unsigned short* Bsw1    = (unsigned short*)(ws + 262144);    // 262144 B
  float*          wbuf    = (float*)(ws + 655360);             // 786432 B
  int*            counts  = (int*)(ws + 1441792);              // 262144 B
  int*            offsets = (int*)(ws + 1703936);              // 262144 B
  unsigned short* edges   = (unsigned short*)(ws + 2228224);   // 393216 B
  // bf16 state sink (masked contrib) — only if workspace is big enough
  const size_t SBASE = 2621440;                                // 16B aligned
  const size_t SB    = (size_t)BN * 128 * 2;                   // 16 MiB each
  int useb = (ws_size >= SBASE + 4*SB) ? 1 : 0;
  unsigned short* sc0 = (unsigned short*)(ws + SBASE + 0*SB);
  unsigned short* sh0 = (unsigned short*)(ws + SBASE + 1*SB);
  unsigned short* sc1 = (unsigned short*)(ws + SBASE + 2*SB);
  unsigned short* sh1 = (unsigned short*)(ws + SBASE + 3*SB);

  // prep: CSR build (32 blocks) + B pre-swizzle (32 blocks), one launch
  kprep<<<64, 1024, 0, stream>>>(ri, ti, fi, counts, offsets, edges,
                                 Wi0, Wh0, Wi1, Wh1, Bsw0, Bsw1);

  // fused 2-layer LSTM (r2 schedule); skips done batches; masked contrib to
  // bf16 ws (or predicated f32 in-place fallback)
  klstm2<<<BN/ROWSB, 512, 0, stream>>>(ne, c0, h0, c1, h1,
                                       sc0, sh0, sc1, sh1,
                                       Bsw0, b0, Bsw1, b1,
                                       ei, rni, sl, cs, useb);

  // decisions
  kdec<<<BN/4, 256, 0, stream>>>(c0, h0, c1, h1, sc0, sh0, sc1, sh1,
                                 Wr, br, Wb, bb, ip, ei, rni, wbuf, useb);

  kagg<<<BN/4, 512, 0, stream>>>(c0, h0, c1, h1, sc0, sh0, sc1, sh1,
                                 ip, wbuf, edges, counts, offsets,
                                 sl, cs, out, useb);
}

// Round 10
// 419.191 us; speedup vs baseline: 1.5982x; 1.0127x over previous
//
#include <hip/hip_runtime.h>
#include <stdint.h>

#define BB 32
#define NN 2048
#define HH 128
#define BN (BB*NN)

typedef short v8s __attribute__((ext_vector_type(8)));
typedef float v4f __attribute__((ext_vector_type(4)));

__device__ __forceinline__ unsigned short f2b(float f){
  union { float f; unsigned int i; } v; v.f = f;
  unsigned int x = v.i;
  unsigned int r = x + 0x7FFFu + ((x >> 16) & 1u);   // RNE f32 -> bf16
  return (unsigned short)(r >> 16);
}
__device__ __forceinline__ unsigned int pk2(float a, float b){
  return (unsigned int)f2b(a) | ((unsigned int)f2b(b) << 16);
}
__device__ __forceinline__ float b2f(unsigned int s){
  union { unsigned int i; float f; } v; v.i = s << 16; return v.f;
}
__device__ __forceinline__ float frcp(float x){ return __builtin_amdgcn_rcpf(x); }
// fast sigmoid / tanh: v_exp + v_rcp, ~1e-6 rel err (<< bf16 gate noise)
__device__ __forceinline__ float fsigm(float x){ return frcp(1.0f + __expf(-x)); }
__device__ __forceinline__ float ftanh(float x){ return 1.0f - 2.0f*frcp(1.0f + __expf(2.0f*x)); }

// ---------------- pre-swizzle B = [Wi;Wh] (f32) into bf16 MFMA fragment order
// must finish before klstm2 -> tiny standalone launch
__global__ __launch_bounds__(512) void kswz(
    const float* __restrict__ Wi0, const float* __restrict__ Wh0,
    const float* __restrict__ Wi1, const float* __restrict__ Wh1,
    unsigned short* __restrict__ Bsw0, unsigned short* __restrict__ Bsw1){
  int idx = blockIdx.x*512 + threadIdx.x;   // 0..32767
  int bid = idx >> 6;                       // 0..511
  int lane = idx & 63;
  int layer = bid >> 8;
  int kc = (bid >> 5) & 7;
  int ct = bid & 31;
  const float* Wi = layer ? Wi1 : Wi0;
  const float* Wh = layer ? Wh1 : Wh0;
  unsigned short* dst = layer ? Bsw1 : Bsw0;
  int col = ct*16 + (lane & 15);
  int kbase = kc*32 + (lane >> 4)*8;
  size_t o = ((size_t)(kc*32 + ct)*64 + (size_t)lane)*8;
  #pragma unroll
  for (int j = 0; j < 8; j++){
    int k = kbase + j;
    dst[o + j] = f2b((k < 128) ? Wi[k*512 + col] : Wh[(k-128)*512 + col]);
  }
}

// ---------------- fused 2-layer LSTM + hidden CSR build ---------------------
// Blocks 0..31: CSR build (one batch each; output consumed only by kagg, two
// launches later -> fully hidden under the LSTM blocks).
// Blocks 32..2079: LSTM tile of 32 rows (r2 schedule, bf16 state sink).
// LDS overlaid via union (34 KB either way).
#define ROWSB 32
#define PA 264   // ushorts/row of A tile: 256 + 8 pad
#define PH 136   // ushorts/row of H tiles: 128 + 8 pad

struct LstmLds {
  unsigned short A[ROWSB*PA];   // [ne | h0_old] bf16
  unsigned short H[ROWSB*PH];   // h1_old bf16
  unsigned short G[ROWSB*PH];   // h0_new bf16
};
struct CsrLds {
  int cnt[NN];
  int off[NN];
  int cur[NN];
  int wpart[8];
};

__global__ __launch_bounds__(512, 4) void klstm2(
    const float* __restrict__ ne,
    float* __restrict__ c0, float* __restrict__ h0,
    float* __restrict__ c1, float* __restrict__ h1,
    unsigned short* __restrict__ sc0, unsigned short* __restrict__ sh0,
    unsigned short* __restrict__ sc1, unsigned short* __restrict__ sh1,
    const unsigned short* __restrict__ Bsw0, const float* __restrict__ b0,
    const unsigned short* __restrict__ Bsw1, const float* __restrict__ b1,
    const int* __restrict__ exit_idx, const int* __restrict__ raise_idx,
    const int* __restrict__ ri, const int* __restrict__ ti,
    const int* __restrict__ fi,
    int* __restrict__ counts, int* __restrict__ offsets,
    unsigned short* __restrict__ edges,
    const int* __restrict__ step_limits, const int* __restrict__ cur_step,
    int useb)
{
  __shared__ union { LstmLds l; CsrLds c; } u;

  int tid = threadIdx.x;

  if (blockIdx.x < 32){
    // ================= CSR build for batch b (hidden under LSTM) ===========
    int b = blockIdx.x;
    const int* rp = ri + b*NN;
    const int* tp = ti + b*NN;
    const int* fp = fi + b*NN;

    #pragma unroll
    for (int p = 0; p < 4; p++){ u.c.cnt[p*512 + tid] = 0; u.c.cur[p*512 + tid] = 0; }
    __syncthreads();

    int rv[4], tv[4], fv[4];
    #pragma unroll
    for (int p = 0; p < 4; p++){
      int n = p*512 + tid;
      rv[p] = rp[n]; tv[p] = tp[n]; fv[p] = fp[n];
      atomicAdd(&u.c.cnt[rv[p]], 1);
      atomicAdd(&u.c.cnt[tv[p]], 1);
      atomicAdd(&u.c.cnt[fv[p]], 1);
    }
    __syncthreads();

    // exclusive scan over 2048 counts: thread owns 4 consecutive
    int cc0 = u.c.cnt[4*tid], cc1 = u.c.cnt[4*tid+1];
    int cc2 = u.c.cnt[4*tid+2], cc3 = u.c.cnt[4*tid+3];
    int s = cc0 + cc1 + cc2 + cc3;
    int lane = tid & 63, wv = tid >> 6;
    int inc = s;
    #pragma unroll
    for (int d = 1; d < 64; d <<= 1){
      int t = __shfl_up(inc, d, 64);
      if (lane >= d) inc += t;
    }
    if (lane == 63) u.c.wpart[wv] = inc;
    __syncthreads();
    if (tid == 0){
      int run = 0;
      #pragma unroll
      for (int w = 0; w < 8; w++){ int t = u.c.wpart[w]; u.c.wpart[w] = run; run += t; }
    }
    __syncthreads();
    int excl = u.c.wpart[wv] + inc - s;
    u.c.off[4*tid]   = excl;
    u.c.off[4*tid+1] = excl + cc0;
    u.c.off[4*tid+2] = excl + cc0 + cc1;
    u.c.off[4*tid+3] = excl + cc0 + cc1 + cc2;
    offsets[b*NN + 4*tid]   = excl;
    offsets[b*NN + 4*tid+1] = excl + cc0;
    offsets[b*NN + 4*tid+2] = excl + cc0 + cc1;
    offsets[b*NN + 4*tid+3] = excl + cc0 + cc1 + cc2;
    counts[b*NN + 4*tid]   = cc0;
    counts[b*NN + 4*tid+1] = cc1;
    counts[b*NN + 4*tid+2] = cc2;
    counts[b*NN + 4*tid+3] = cc3;
    __syncthreads();

    size_t ebase = (size_t)b*3*NN;
    #pragma unroll
    for (int p = 0; p < 4; p++){
      int n = p*512 + tid;
      int t0 = rv[p]; int p0 = atomicAdd(&u.c.cur[t0], 1);
      edges[ebase + u.c.off[t0] + p0] = (unsigned short)n;
      int t1 = tv[p]; int p1 = atomicAdd(&u.c.cur[t1], 1);
      edges[ebase + u.c.off[t1] + p1] = (unsigned short)(n | (1<<11));
      int t2 = fv[p]; int p2 = atomicAdd(&u.c.cur[t2], 1);
      edges[ebase + u.c.off[t2] + p2] = (unsigned short)(n | (2<<11));
    }
    return;
  }

  // ================= LSTM tile =============================================
  int rowbase = (blockIdx.x - 32) * ROWSB;    // 32 rows, never crosses a batch
  int b = rowbase >> 11;
  if (cur_step[0] >= step_limits[b]) return;  // done batch: keep old states

  int wid = tid >> 6, lane = tid & 63;
  int quad = lane >> 4, l16 = lane & 15;
  int ch = wid*16 + l16;            // channel within each gate (0..127)
  int e_row = exit_idx[b], r_row = raise_idx[b];   // NODE indices (0..2047)

  // ---- stage A0 = bf16([ne | h0_old]) : 4 float4 per thread ----
  #pragma unroll
  for (int p = 0; p < 4; p++){
    int idx = p*512 + tid;
    int row = idx >> 6, chunk = idx & 63;     // chunk = float4 index (0..63)
    size_t g = (size_t)(rowbase + row)*128 + (chunk & 31)*4;
    float4 v = (chunk < 32) ? *(const float4*)(ne + g) : *(const float4*)(h0 + g);
    uint2 w; w.x = pk2(v.x, v.y); w.y = pk2(v.z, v.w);
    *(uint2*)&u.l.A[row*PA + chunk*4] = w;
  }
  __syncthreads();

  // ---- prefetch c0 rows + layer-0 biases (independent of LDS; hidden by GEMM0)
  float cpre[8], bias[4];
  #pragma unroll
  for (int rt = 0; rt < 2; rt++)
    #pragma unroll
    for (int r = 0; r < 4; r++)
      cpre[rt*4+r] = c0[((size_t)rowbase + rt*16 + quad*4 + r)*128 + ch];
  #pragma unroll
  for (int g = 0; g < 4; g++) bias[g] = b0[g*128 + ch];

  // ---- stage H1 = bf16(h1_old) during GEMM0's shadow (consumed after b2) ----
  #pragma unroll
  for (int p = 0; p < 2; p++){
    int idx = p*512 + tid;
    int row = idx >> 5, chunk = idx & 31;
    float4 v = *(const float4*)(h1 + (size_t)(rowbase + row)*128 + chunk*4);
    uint2 w; w.x = pk2(v.x, v.y); w.y = pk2(v.z, v.w);
    *(uint2*)&u.l.H[row*PH + chunk*4] = w;
  }

  // ================= layer 0: gates = [ne|h0_old] @ B0 =================
  const v8s* Bv0 = (const v8s*)Bsw0;
  v4f acc[2][4] = {};
  v8s bc[4], bn[4];
  #pragma unroll
  for (int g = 0; g < 4; g++) bc[g] = Bv0[(size_t)(g*8 + wid)*64 + lane];
  #pragma unroll
  for (int kc = 0; kc < 8; kc++){
    if (kc < 7){
      #pragma unroll
      for (int g = 0; g < 4; g++) bn[g] = Bv0[(size_t)((kc+1)*32 + g*8 + wid)*64 + lane];
    }
    v8s a0 = *(const v8s*)&u.l.A[(0*16 + l16)*PA + kc*32 + quad*8];
    v8s a1 = *(const v8s*)&u.l.A[(1*16 + l16)*PA + kc*32 + quad*8];
    #pragma unroll
    for (int g = 0; g < 4; g++){
      acc[0][g] = __builtin_amdgcn_mfma_f32_16x16x32_bf16(a0, bc[g], acc[0][g], 0,0,0);
      acc[1][g] = __builtin_amdgcn_mfma_f32_16x16x32_bf16(a1, bc[g], acc[1][g], 0,0,0);
    }
    #pragma unroll
    for (int g = 0; g < 4; g++) bc[g] = bn[g];
  }

  // ---- epilogue 0: LSTM update; h0_new -> ldsG; state -> bf16 ws or f32 ----
  #pragma unroll
  for (int rt = 0; rt < 2; rt++){
    #pragma unroll
    for (int r = 0; r < 4; r++){
      int k = rt*4 + r;
      int lrow = rt*16 + quad*4 + r;
      int grow = rowbase + lrow;
      int node = grow & 2047;
      bool special = (node == e_row) || (node == r_row);
      float iv = acc[rt][0][r] + bias[0];
      float fv = acc[rt][1][r] + bias[1];
      float gv = acc[rt][2][r] + bias[2];
      float ov = acc[rt][3][r] + bias[3];
      float cn = fsigm(fv)*cpre[k] + fsigm(iv)*ftanh(gv);
      float hn = fsigm(ov)*ftanh(cn);
      if (useb){
        // masked contrib in bf16: special rows hold OLD state
        sc0[(size_t)grow*128 + ch] = special ? f2b(cpre[k]) : f2b(cn);
        sh0[(size_t)grow*128 + ch] = special ? u.l.A[lrow*PA + 128 + ch] : f2b(hn);
      } else if (!special){
        c0[(size_t)grow*128 + ch] = cn;
        h0[(size_t)grow*128 + ch] = hn;
      }
      u.l.G[lrow*PH + ch] = f2b(hn);   // layer-1 A operand (UNMASKED h0n, per ref)
    }
  }

  // ---- prefetch c1 rows + layer-1 bias + first B1 frags (pre-barrier) ----
  #pragma unroll
  for (int rt = 0; rt < 2; rt++)
    #pragma unroll
    for (int r = 0; r < 4; r++)
      cpre[rt*4+r] = c1[((size_t)rowbase + rt*16 + quad*4 + r)*128 + ch];
  #pragma unroll
  for (int g = 0; g < 4; g++) bias[g] = b1[g*128 + ch];
  const v8s* Bv1 = (const v8s*)Bsw1;
  #pragma unroll
  for (int g = 0; g < 4; g++) bc[g] = Bv1[(size_t)(g*8 + wid)*64 + lane];

  __syncthreads();   // h0_new + h1_old LDS tiles complete

  // ================= layer 1: gates = [h0_new | h1_old] @ B1 =================
  #pragma unroll
  for (int rt = 0; rt < 2; rt++)
    #pragma unroll
    for (int g = 0; g < 4; g++)
      acc[rt][g] = (v4f){0.f, 0.f, 0.f, 0.f};
  #pragma unroll
  for (int kc = 0; kc < 8; kc++){
    if (kc < 7){
      #pragma unroll
      for (int g = 0; g < 4; g++) bn[g] = Bv1[(size_t)((kc+1)*32 + g*8 + wid)*64 + lane];
    }
    v8s a0, a1;
    if (kc < 4){
      a0 = *(const v8s*)&u.l.G[(0*16 + l16)*PH + kc*32 + quad*8];
      a1 = *(const v8s*)&u.l.G[(1*16 + l16)*PH + kc*32 + quad*8];
    } else {
      a0 = *(const v8s*)&u.l.H[(0*16 + l16)*PH + (kc-4)*32 + quad*8];
      a1 = *(const v8s*)&u.l.H[(1*16 + l16)*PH + (kc-4)*32 + quad*8];
    }
    #pragma unroll
    for (int g = 0; g < 4; g++){
      acc[0][g] = __builtin_amdgcn_mfma_f32_16x16x32_bf16(a0, bc[g], acc[0][g], 0,0,0);
      acc[1][g] = __builtin_amdgcn_mfma_f32_16x16x32_bf16(a1, bc[g], acc[1][g], 0,0,0);
    }
    #pragma unroll
    for (int g = 0; g < 4; g++) bc[g] = bn[g];
  }

  // ---- epilogue 1 ----
  #pragma unroll
  for (int rt = 0; rt < 2; rt++){
    #pragma unroll
    for (int r = 0; r < 4; r++){
      int k = rt*4 + r;
      int lrow = rt*16 + quad*4 + r;
      int grow = rowbase + lrow;
      int node = grow & 2047;
      bool special = (node == e_row) || (node == r_row);
      float iv = acc[rt][0][r] + bias[0];
      float fv = acc[rt][1][r] + bias[1];
      float gv = acc[rt][2][r] + bias[2];
      float ov = acc[rt][3][r] + bias[3];
      float cn = fsigm(fv)*cpre[k] + fsigm(iv)*ftanh(gv);
      float hn = fsigm(ov)*ftanh(cn);
      if (useb){
        sc1[(size_t)grow*128 + ch] = special ? f2b(cpre[k]) : f2b(cn);
        sh1[(size_t)grow*128 + ch] = special ? u.l.H[lrow*PH + ch] : f2b(hn);
      } else if (!special){
        c1[(size_t)grow*128 + ch] = cn;
        h1[(size_t)grow*128 + ch] = hn;
      }
    }
  }
}

// ---------------- decisions: softmax(hs @ W) -> edge weights wr/wt/wf -------
__global__ __launch_bounds__(256) void kdec(
    const float* __restrict__ c0, const float* __restrict__ h0,
    const float* __restrict__ c1, const float* __restrict__ h1,
    const unsigned short* __restrict__ sc0, const unsigned short* __restrict__ sh0,
    const unsigned short* __restrict__ sc1, const unsigned short* __restrict__ sh1,
    const float* __restrict__ Wr, const float* __restrict__ br,
    const float* __restrict__ Wb, const float* __restrict__ bb,
    const float* __restrict__ ip,
    const int* __restrict__ exit_idx, const int* __restrict__ raise_idx,
    float* __restrict__ wbuf, int useb)
{
  int tid = threadIdx.x;
  int wid = tid >> 6, lane = tid & 63;
  int gid = blockIdx.x*4 + wid;          // node id
  int b = gid >> 11, n = gid & 2047;

  float hv[8];
  if (useb){
    const unsigned short* bufs16[4] = {sc0, sh0, sc1, sh1};
    const unsigned short* hb = bufs16[lane >> 4] + (size_t)gid*128 + (lane & 15)*8;
    uint4 raw = *(const uint4*)hb;        // 8 bf16
    hv[0] = b2f(raw.x & 0xffffu); hv[1] = b2f(raw.x >> 16);
    hv[2] = b2f(raw.y & 0xffffu); hv[3] = b2f(raw.y >> 16);
    hv[4] = b2f(raw.z & 0xffffu); hv[5] = b2f(raw.z >> 16);
    hv[6] = b2f(raw.w & 0xffffu); hv[7] = b2f(raw.w >> 16);
  } else {
    const float* bufs[4] = {c0, h0, c1, h1};
    const float* hb = bufs[lane >> 4] + (size_t)gid*128 + (lane & 15)*8;
    float4 hv0 = *(const float4*)hb;
    float4 hv1 = *(const float4*)(hb + 4);
    hv[0]=hv0.x; hv[1]=hv0.y; hv[2]=hv0.z; hv[3]=hv0.w;
    hv[4]=hv1.x; hv[5]=hv1.y; hv[6]=hv1.z; hv[7]=hv1.w;
  }
  const float* wrp = Wr + lane*16;
  const float* wbp = Wb + lane*16;
  float r0=0.f, r1=0.f, q0=0.f, q1=0.f;
  #pragma unroll
  for (int j = 0; j < 8; j++){
    float h = hv[j];
    r0 += h * wrp[j*2];  r1 += h * wrp[j*2+1];
    q0 += h * wbp[j*2];  q1 += h * wbp[j*2+1];
  }
  #pragma unroll
  for (int off = 32; off > 0; off >>= 1){
    r0 += __shfl_xor(r0, off, 64);
    r1 += __shfl_xor(r1, off, 64);
    q0 += __shfl_xor(q0, off, 64);
    q1 += __shfl_xor(q1, off, 64);
  }
  if (lane == 0){
    r0 += br[0]; r1 += br[1];
    q0 += bb[0]; q1 += bb[1];
    float pr, pn;
    if (n == exit_idx[b] || n == raise_idx[b]){ pr = 0.f; pn = 1.f; }
    else {
      float m = fmaxf(r0, r1);
      float e0 = __expf(r0 - m), e1 = __expf(r1 - m);
      pr = e0 / (e0 + e1); pn = e1 / (e0 + e1);
    }
    float m2 = fmaxf(q0, q1);
    float f0 = __expf(q0 - m2), f1 = __expf(q1 - m2);
    float pt = f0 / (f0 + f1), pf = f1 / (f0 + f1);
    float ipv = ip[gid];
    wbuf[0*BN + gid] = pr * ipv;
    wbuf[1*BN + gid] = pn * pt * ipv;
    wbuf[2*BN + gid] = pn * pf * ipv;
  }
}

// ---------------- gather + normalize + output (4 nodes / block) -------------
// Non-temporal stores on `out` (write-once, 134 MB) keep the bf16 state
// resident in L2/L3 for the gathers.
__global__ __launch_bounds__(512) void kagg(
    const float* __restrict__ c0, const float* __restrict__ h0,
    const float* __restrict__ c1, const float* __restrict__ h1,
    const unsigned short* __restrict__ sc0, const unsigned short* __restrict__ sh0,
    const unsigned short* __restrict__ sc1, const unsigned short* __restrict__ sh1,
    const float* __restrict__ ip,
    const float* __restrict__ wbuf, const unsigned short* __restrict__ edges,
    const int* __restrict__ counts, const int* __restrict__ offsets,
    const int* __restrict__ step_limits, const int* __restrict__ cur_step,
    float* __restrict__ out, int useb)
{
  int tid0 = threadIdx.x;
  int sub = tid0 >> 7;             // node within block (0..3)
  int tid = tid0 & 127;            // 0..127, channels tid*4..tid*4+3
  int gid = blockIdx.x*4 + sub;    // b*N + j
  int b = gid >> 11;
  size_t obase = (size_t)gid*513;
  const float* bufs[4] = {c0, h0, c1, h1};

  if (cur_step[0] >= step_limits[b]){       // done: copy old state + old ip
    int c = tid*4;
    const float* s = bufs[c >> 7];
    size_t rb = (size_t)gid*128 + (c & 127);
    __builtin_nontemporal_store(s[rb+0], &out[obase + c+0]);
    __builtin_nontemporal_store(s[rb+1], &out[obase + c+1]);
    __builtin_nontemporal_store(s[rb+2], &out[obase + c+2]);
    __builtin_nontemporal_store(s[rb+3], &out[obase + c+3]);
    if (tid == 0) __builtin_nontemporal_store(ip[gid], &out[obase + 512]);
    return;
  }

  int cnt = counts[gid], off = offsets[gid];
  const unsigned short* eb = edges + (size_t)b*3*NN + off;
  int lane = tid & 63;
  int coff = (tid & 31)*4;
  float a0=0.f, a1=0.f, a2=0.f, a3=0.f, ipn=0.f;

  if (useb){
    const unsigned short* bufs16[4] = {sc0, sh0, sc1, sh1};
    const unsigned short* sb = bufs16[tid >> 5];
    for (int base = 0; base < cnt; base += 64){
      int e = base + lane;
      int n_l = 0; float w_l = 0.f;
      if (e < cnt){
        int pk = eb[e];
        n_l = pk & 2047;
        w_l = wbuf[(pk >> 11)*BN + (b<<11) + n_l];
      }
      int m = min(cnt - base, 64);
      for (int j = 0; j < m; j++){
        int   n = __shfl(n_l, j, 64);
        float w = __shfl(w_l, j, 64);
        uint2 raw = *(const uint2*)(sb + ((size_t)(b<<11) + n)*128 + coff);
        ipn += w;
        a0 += w * b2f(raw.x & 0xffffu);
        a1 += w * b2f(raw.x >> 16);
        a2 += w * b2f(raw.y & 0xffffu);
        a3 += w * b2f(raw.y >> 16);
      }
    }
  } else {
    const float* sb = bufs[tid >> 5];
    for (int base = 0; base < cnt; base += 64){
      int e = base + lane;
      int n_l = 0; float w_l = 0.f;
      if (e < cnt){
        int pk = eb[e];
        n_l = pk & 2047;
        w_l = wbuf[(pk >> 11)*BN + (b<<11) + n_l];
      }
      int m = min(cnt - base, 64);
      for (int j = 0; j < m; j++){
        int   n = __shfl(n_l, j, 64);
        float w = __shfl(w_l, j, 64);
        float4 sv = *(const float4*)(sb + ((size_t)(b<<11) + n)*128 + coff);
        ipn += w;
        a0 += w * sv.x;
        a1 += w * sv.y;
        a2 += w * sv.z;
        a3 += w * sv.w;
      }
    }
  }
  int c = tid*4;
  float inv = 1.0f / (ipn + 1e-7f);
  __builtin_nontemporal_store(a0*inv, &out[obase + c+0]);
  __builtin_nontemporal_store(a1*inv, &out[obase + c+1]);
  __builtin_nontemporal_store(a2*inv, &out[obase + c+2]);
  __builtin_nontemporal_store(a3*inv, &out[obase + c+3]);
  if (tid == 0) __builtin_nontemporal_store(ipn, &out[obase + 512]);
}

extern "C" void kernel_launch(void* const* d_in, const int* in_sizes, int n_in,
                              void* d_out, int out_size, void* d_ws, size_t ws_size,
                              hipStream_t stream){
  const float* ne  = (const float*)d_in[0];
  float* c0  = (float*)d_in[1];   // updated in place only in f32-fallback mode
  float* h0  = (float*)d_in[2];
  float* c1  = (float*)d_in[3];
  float* h1  = (float*)d_in[4];
  const float* ip  = (const float*)d_in[5];
  const float* Wi0 = (const float*)d_in[6];
  const float* Wh0 = (const float*)d_in[7];
  const float* b0  = (const float*)d_in[8];
  const float* Wi1 = (const float*)d_in[9];
  const float* Wh1 = (const float*)d_in[10];
  const float* b1  = (const float*)d_in[11];
  const float* Wr  = (const float*)d_in[12];
  const float* br  = (const float*)d_in[13];
  const float* Wb  = (const float*)d_in[14];
  const float* bb  = (const float*)d_in[15];
  const int* ti  = (const int*)d_in[16];
  const int* fi  = (const int*)d_in[17];
  const int* ri  = (const int*)d_in[18];
  const int* ei  = (const int*)d_in[19];
  const int* rni = (const int*)d_in[20];
  const int* sl  = (const int*)d_in[21];
  const int* cs  = (const int*)d_in[22];
  float* out = (float*)d_out;

  // --- ws layout ---
  uint8_t* ws = (uint8_t*)d_ws;
  unsigned short* Bsw0    = (unsigned short*)(ws + 0);         // 262144 B
  unsigned short* Bsw1    = (unsigned short*)(ws + 262144);    // 262144 B
  float*          wbuf    = (float*)(ws + 655360);             // 786432 B
  int*            counts  = (int*)(ws + 1441792);              // 262144 B
  int*            offsets = (int*)(ws + 1703936);              // 262144 B
  unsigned short* edges   = (unsigned short*)(ws + 2228224);   // 393216 B
  // bf16 state sink (masked contrib) — only if workspace is big enough
  const size_t SBASE = 2621440;                                // 16B aligned
  const size_t SB    = (size_t)BN * 128 * 2;                   // 16 MiB each
  int useb = (ws_size >= SBASE + 4*SB) ? 1 : 0;
  unsigned short* sc0 = (unsigned short*)(ws + SBASE + 0*SB);
  unsigned short* sh0 = (unsigned short*)(ws + SBASE + 1*SB);
  unsigned short* sc1 = (unsigned short*)(ws + SBASE + 2*SB);
  unsigned short* sh1 = (unsigned short*)(ws + SBASE + 3*SB);

  // B pre-swizzle (must precede klstm2)
  kswz<<<64, 512, 0, stream>>>(Wi0, Wh0, Wi1, Wh1, Bsw0, Bsw1);

  // fused 2-layer LSTM (blocks 32..2079) + CSR build (blocks 0..31, hidden)
  klstm2<<<32 + BN/ROWSB, 512, 0, stream>>>(ne, c0, h0, c1, h1,
                                            sc0, sh0, sc1, sh1,
                                            Bsw0, b0, Bsw1, b1,
                                            ei, rni, ri, ti, fi,
                                            counts, offsets, edges,
                                            sl, cs, useb);

  // decisions
  kdec<<<BN/4, 256, 0, stream>>>(c0, h0, c1, h1, sc0, sh0, sc1, sh1,
                                 Wr, br, Wb, bb, ip, ei, rni, wbuf, useb);

  kagg<<<BN/4, 512, 0, stream>>>(c0, h0, c1, h1, sc0, sh0, sc1, sh1,
                                 ip, wbuf, edges, counts, offsets,
                                 sl, cs, out, useb);
}

// Round 11
// 417.093 us; speedup vs baseline: 1.6063x; 1.0050x over previous
//
#include <hip/hip_runtime.h>
#include <stdint.h>

#define BB 32
#define NN 2048
#define HH 128
#define BN (BB*NN)

typedef short v8s __attribute__((ext_vector_type(8)));
typedef float v4f __attribute__((ext_vector_type(4)));

__device__ __forceinline__ unsigned short f2b(float f){
  union { float f; unsigned int i; } v; v.f = f;
  unsigned int x = v.i;
  unsigned int r = x + 0x7FFFu + ((x >> 16) & 1u);   // RNE f32 -> bf16
  return (unsigned short)(r >> 16);
}
__device__ __forceinline__ unsigned int pk2(float a, float b){
  return (unsigned int)f2b(a) | ((unsigned int)f2b(b) << 16);
}
__device__ __forceinline__ float b2f(unsigned int s){
  union { unsigned int i; float f; } v; v.i = s << 16; return v.f;
}
__device__ __forceinline__ float frcp(float x){ return __builtin_amdgcn_rcpf(x); }
// fast sigmoid / tanh: v_exp + v_rcp, ~1e-6 rel err (<< bf16 gate noise)
__device__ __forceinline__ float fsigm(float x){ return frcp(1.0f + __expf(-x)); }
__device__ __forceinline__ float ftanh(float x){ return 1.0f - 2.0f*frcp(1.0f + __expf(2.0f*x)); }

// ---------------- pre-swizzle B = [Wi;Wh] (f32) into bf16 MFMA fragment order
__global__ __launch_bounds__(512) void kswz(
    const float* __restrict__ Wi0, const float* __restrict__ Wh0,
    const float* __restrict__ Wi1, const float* __restrict__ Wh1,
    unsigned short* __restrict__ Bsw0, unsigned short* __restrict__ Bsw1){
  int idx = blockIdx.x*512 + threadIdx.x;   // 0..32767
  int bid = idx >> 6;                       // 0..511
  int lane = idx & 63;
  int layer = bid >> 8;
  int kc = (bid >> 5) & 7;
  int ct = bid & 31;
  const float* Wi = layer ? Wi1 : Wi0;
  const float* Wh = layer ? Wh1 : Wh0;
  unsigned short* dst = layer ? Bsw1 : Bsw0;
  int col = ct*16 + (lane & 15);
  int kbase = kc*32 + (lane >> 4)*8;
  size_t o = ((size_t)(kc*32 + ct)*64 + (size_t)lane)*8;
  #pragma unroll
  for (int j = 0; j < 8; j++){
    int k = kbase + j;
    dst[o + j] = f2b((k < 128) ? Wi[k*512 + col] : Wh[(k-128)*512 + col]);
  }
}

// ---------------- fused 2-layer LSTM + hidden CSR build ---------------------
// Blocks 0..31: CSR build. Blocks 32..2079: LSTM tile (32 rows).
// State sink: INTERLEAVED bf16  sAll[node][512] = [c0n|h0n|c1n|h1n] (masked
// contrib: exit/raise rows hold OLD state). 2-deep B-fragment prefetch.
#define ROWSB 32
#define PA 264   // ushorts/row of A tile: 256 + 8 pad
#define PH 136   // ushorts/row of H tiles: 128 + 8 pad

struct LstmLds {
  unsigned short A[ROWSB*PA];   // [ne | h0_old] bf16
  unsigned short H[ROWSB*PH];   // h1_old bf16
  unsigned short G[ROWSB*PH];   // h0_new bf16
};
struct CsrLds {
  int cnt[NN];
  int off[NN];
  int cur[NN];
  int wpart[8];
};

__global__ __launch_bounds__(512, 4) void klstm2(
    const float* __restrict__ ne,
    float* __restrict__ c0, float* __restrict__ h0,
    float* __restrict__ c1, float* __restrict__ h1,
    unsigned short* __restrict__ sAll,
    const unsigned short* __restrict__ Bsw0, const float* __restrict__ b0,
    const unsigned short* __restrict__ Bsw1, const float* __restrict__ b1,
    const int* __restrict__ exit_idx, const int* __restrict__ raise_idx,
    const int* __restrict__ ri, const int* __restrict__ ti,
    const int* __restrict__ fi,
    int* __restrict__ counts, int* __restrict__ offsets,
    unsigned short* __restrict__ edges,
    const int* __restrict__ step_limits, const int* __restrict__ cur_step,
    int useb)
{
  __shared__ union { LstmLds l; CsrLds c; } u;

  int tid = threadIdx.x;

  if (blockIdx.x < 32){
    // ================= CSR build for batch b (hidden under LSTM) ===========
    int b = blockIdx.x;
    const int* rp = ri + b*NN;
    const int* tp = ti + b*NN;
    const int* fp = fi + b*NN;

    #pragma unroll
    for (int p = 0; p < 4; p++){ u.c.cnt[p*512 + tid] = 0; u.c.cur[p*512 + tid] = 0; }
    __syncthreads();

    int rv[4], tv[4], fv[4];
    #pragma unroll
    for (int p = 0; p < 4; p++){
      int n = p*512 + tid;
      rv[p] = rp[n]; tv[p] = tp[n]; fv[p] = fp[n];
      atomicAdd(&u.c.cnt[rv[p]], 1);
      atomicAdd(&u.c.cnt[tv[p]], 1);
      atomicAdd(&u.c.cnt[fv[p]], 1);
    }
    __syncthreads();

    // exclusive scan over 2048 counts: thread owns 4 consecutive
    int cc0 = u.c.cnt[4*tid], cc1 = u.c.cnt[4*tid+1];
    int cc2 = u.c.cnt[4*tid+2], cc3 = u.c.cnt[4*tid+3];
    int s = cc0 + cc1 + cc2 + cc3;
    int lane = tid & 63, wv = tid >> 6;
    int inc = s;
    #pragma unroll
    for (int d = 1; d < 64; d <<= 1){
      int t = __shfl_up(inc, d, 64);
      if (lane >= d) inc += t;
    }
    if (lane == 63) u.c.wpart[wv] = inc;
    __syncthreads();
    if (tid == 0){
      int run = 0;
      #pragma unroll
      for (int w = 0; w < 8; w++){ int t = u.c.wpart[w]; u.c.wpart[w] = run; run += t; }
    }
    __syncthreads();
    int excl = u.c.wpart[wv] + inc - s;
    u.c.off[4*tid]   = excl;
    u.c.off[4*tid+1] = excl + cc0;
    u.c.off[4*tid+2] = excl + cc0 + cc1;
    u.c.off[4*tid+3] = excl + cc0 + cc1 + cc2;
    offsets[b*NN + 4*tid]   = excl;
    offsets[b*NN + 4*tid+1] = excl + cc0;
    offsets[b*NN + 4*tid+2] = excl + cc0 + cc1;
    offsets[b*NN + 4*tid+3] = excl + cc0 + cc1 + cc2;
    counts[b*NN + 4*tid]   = cc0;
    counts[b*NN + 4*tid+1] = cc1;
    counts[b*NN + 4*tid+2] = cc2;
    counts[b*NN + 4*tid+3] = cc3;
    __syncthreads();

    size_t ebase = (size_t)b*3*NN;
    #pragma unroll
    for (int p = 0; p < 4; p++){
      int n = p*512 + tid;
      int t0 = rv[p]; int p0 = atomicAdd(&u.c.cur[t0], 1);
      edges[ebase + u.c.off[t0] + p0] = (unsigned short)n;
      int t1 = tv[p]; int p1 = atomicAdd(&u.c.cur[t1], 1);
      edges[ebase + u.c.off[t1] + p1] = (unsigned short)(n | (1<<11));
      int t2 = fv[p]; int p2 = atomicAdd(&u.c.cur[t2], 1);
      edges[ebase + u.c.off[t2] + p2] = (unsigned short)(n | (2<<11));
    }
    return;
  }

  // ================= LSTM tile =============================================
  int rowbase = (blockIdx.x - 32) * ROWSB;    // 32 rows, never crosses a batch
  int b = rowbase >> 11;
  if (cur_step[0] >= step_limits[b]) return;  // done batch: keep old states

  int wid = tid >> 6, lane = tid & 63;
  int quad = lane >> 4, l16 = lane & 15;
  int ch = wid*16 + l16;            // channel within each gate (0..127)
  int e_row = exit_idx[b], r_row = raise_idx[b];   // NODE indices (0..2047)

  // ---- stage A0 = bf16([ne | h0_old]) : 4 float4 per thread ----
  #pragma unroll
  for (int p = 0; p < 4; p++){
    int idx = p*512 + tid;
    int row = idx >> 6, chunk = idx & 63;     // chunk = float4 index (0..63)
    size_t g = (size_t)(rowbase + row)*128 + (chunk & 31)*4;
    float4 v = (chunk < 32) ? *(const float4*)(ne + g) : *(const float4*)(h0 + g);
    uint2 w; w.x = pk2(v.x, v.y); w.y = pk2(v.z, v.w);
    *(uint2*)&u.l.A[row*PA + chunk*4] = w;
  }
  __syncthreads();

  // ---- prefetch c0 rows + layer-0 biases (independent of LDS; hidden by GEMM0)
  float cpre[8], bias[4];
  #pragma unroll
  for (int rt = 0; rt < 2; rt++)
    #pragma unroll
    for (int r = 0; r < 4; r++)
      cpre[rt*4+r] = c0[((size_t)rowbase + rt*16 + quad*4 + r)*128 + ch];
  #pragma unroll
  for (int g = 0; g < 4; g++) bias[g] = b0[g*128 + ch];

  // ---- stage H1 = bf16(h1_old) during GEMM0's shadow (consumed after b2) ----
  #pragma unroll
  for (int p = 0; p < 2; p++){
    int idx = p*512 + tid;
    int row = idx >> 5, chunk = idx & 31;
    float4 v = *(const float4*)(h1 + (size_t)(rowbase + row)*128 + chunk*4);
    uint2 w; w.x = pk2(v.x, v.y); w.y = pk2(v.z, v.w);
    *(uint2*)&u.l.H[row*PH + chunk*4] = w;
  }

  // ================= layer 0: gates = [ne|h0_old] @ B0 =================
  const v8s* Bv0 = (const v8s*)Bsw0;
  v4f acc[2][4] = {};
  v8s bc[4], bp1[4], bp2[4];        // 2-deep B prefetch
  #pragma unroll
  for (int g = 0; g < 4; g++) bc[g]  = Bv0[(size_t)(0*32 + g*8 + wid)*64 + lane];
  #pragma unroll
  for (int g = 0; g < 4; g++) bp1[g] = Bv0[(size_t)(1*32 + g*8 + wid)*64 + lane];
  #pragma unroll
  for (int kc = 0; kc < 8; kc++){
    if (kc < 6){
      #pragma unroll
      for (int g = 0; g < 4; g++) bp2[g] = Bv0[(size_t)((kc+2)*32 + g*8 + wid)*64 + lane];
    }
    v8s a0 = *(const v8s*)&u.l.A[(0*16 + l16)*PA + kc*32 + quad*8];
    v8s a1 = *(const v8s*)&u.l.A[(1*16 + l16)*PA + kc*32 + quad*8];
    #pragma unroll
    for (int g = 0; g < 4; g++){
      acc[0][g] = __builtin_amdgcn_mfma_f32_16x16x32_bf16(a0, bc[g], acc[0][g], 0,0,0);
      acc[1][g] = __builtin_amdgcn_mfma_f32_16x16x32_bf16(a1, bc[g], acc[1][g], 0,0,0);
    }
    #pragma unroll
    for (int g = 0; g < 4; g++){ bc[g] = bp1[g]; bp1[g] = bp2[g]; }
  }

  // ---- epilogue 0: LSTM update; h0_new -> ldsG; state -> sAll[+0/+128] -----
  #pragma unroll
  for (int rt = 0; rt < 2; rt++){
    #pragma unroll
    for (int r = 0; r < 4; r++){
      int k = rt*4 + r;
      int lrow = rt*16 + quad*4 + r;
      int grow = rowbase + lrow;
      int node = grow & 2047;
      bool special = (node == e_row) || (node == r_row);
      float iv = acc[rt][0][r] + bias[0];
      float fv = acc[rt][1][r] + bias[1];
      float gv = acc[rt][2][r] + bias[2];
      float ov = acc[rt][3][r] + bias[3];
      float cn = fsigm(fv)*cpre[k] + fsigm(iv)*ftanh(gv);
      float hn = fsigm(ov)*ftanh(cn);
      if (useb){
        unsigned short cnb = special ? f2b(cpre[k]) : f2b(cn);
        unsigned short hnb = special ? u.l.A[lrow*PA + 128 + ch] : f2b(hn);
        sAll[(size_t)grow*512 +       ch] = cnb;
        sAll[(size_t)grow*512 + 128 + ch] = hnb;
      } else if (!special){
        c0[(size_t)grow*128 + ch] = cn;
        h0[(size_t)grow*128 + ch] = hn;
      }
      u.l.G[lrow*PH + ch] = f2b(hn);   // layer-1 A operand (UNMASKED h0n, per ref)
    }
  }

  // ---- prefetch c1 rows + layer-1 bias + first 2 B1 frag sets (pre-barrier)
  #pragma unroll
  for (int rt = 0; rt < 2; rt++)
    #pragma unroll
    for (int r = 0; r < 4; r++)
      cpre[rt*4+r] = c1[((size_t)rowbase + rt*16 + quad*4 + r)*128 + ch];
  #pragma unroll
  for (int g = 0; g < 4; g++) bias[g] = b1[g*128 + ch];
  const v8s* Bv1 = (const v8s*)Bsw1;
  #pragma unroll
  for (int g = 0; g < 4; g++) bc[g]  = Bv1[(size_t)(0*32 + g*8 + wid)*64 + lane];
  #pragma unroll
  for (int g = 0; g < 4; g++) bp1[g] = Bv1[(size_t)(1*32 + g*8 + wid)*64 + lane];

  __syncthreads();   // h0_new + h1_old LDS tiles complete

  // ================= layer 1: gates = [h0_new | h1_old] @ B1 =================
  #pragma unroll
  for (int rt = 0; rt < 2; rt++)
    #pragma unroll
    for (int g = 0; g < 4; g++)
      acc[rt][g] = (v4f){0.f, 0.f, 0.f, 0.f};
  #pragma unroll
  for (int kc = 0; kc < 8; kc++){
    if (kc < 6){
      #pragma unroll
      for (int g = 0; g < 4; g++) bp2[g] = Bv1[(size_t)((kc+2)*32 + g*8 + wid)*64 + lane];
    }
    v8s a0, a1;
    if (kc < 4){
      a0 = *(const v8s*)&u.l.G[(0*16 + l16)*PH + kc*32 + quad*8];
      a1 = *(const v8s*)&u.l.G[(1*16 + l16)*PH + kc*32 + quad*8];
    } else {
      a0 = *(const v8s*)&u.l.H[(0*16 + l16)*PH + (kc-4)*32 + quad*8];
      a1 = *(const v8s*)&u.l.H[(1*16 + l16)*PH + (kc-4)*32 + quad*8];
    }
    #pragma unroll
    for (int g = 0; g < 4; g++){
      acc[0][g] = __builtin_amdgcn_mfma_f32_16x16x32_bf16(a0, bc[g], acc[0][g], 0,0,0);
      acc[1][g] = __builtin_amdgcn_mfma_f32_16x16x32_bf16(a1, bc[g], acc[1][g], 0,0,0);
    }
    #pragma unroll
    for (int g = 0; g < 4; g++){ bc[g] = bp1[g]; bp1[g] = bp2[g]; }
  }

  // ---- epilogue 1: state -> sAll[+256/+384] ----
  #pragma unroll
  for (int rt = 0; rt < 2; rt++){
    #pragma unroll
    for (int r = 0; r < 4; r++){
      int k = rt*4 + r;
      int lrow = rt*16 + quad*4 + r;
      int grow = rowbase + lrow;
      int node = grow & 2047;
      bool special = (node == e_row) || (node == r_row);
      float iv = acc[rt][0][r] + bias[0];
      float fv = acc[rt][1][r] + bias[1];
      float gv = acc[rt][2][r] + bias[2];
      float ov = acc[rt][3][r] + bias[3];
      float cn = fsigm(fv)*cpre[k] + fsigm(iv)*ftanh(gv);
      float hn = fsigm(ov)*ftanh(cn);
      if (useb){
        unsigned short cnb = special ? f2b(cpre[k]) : f2b(cn);
        unsigned short hnb = special ? u.l.H[lrow*PH + ch] : f2b(hn);
        sAll[(size_t)grow*512 + 256 + ch] = cnb;
        sAll[(size_t)grow*512 + 384 + ch] = hnb;
      } else if (!special){
        c1[(size_t)grow*128 + ch] = cn;
        h1[(size_t)grow*128 + ch] = hn;
      }
    }
  }
}

// ---------------- decisions: softmax(hs @ W) -> edge weights wr/wt/wf -------
// 8 nodes per 512-thread block; one contiguous 1KB bf16 row per wave.
__global__ __launch_bounds__(512) void kdec(
    const float* __restrict__ c0, const float* __restrict__ h0,
    const float* __restrict__ c1, const float* __restrict__ h1,
    const unsigned short* __restrict__ sAll,
    const float* __restrict__ Wr, const float* __restrict__ br,
    const float* __restrict__ Wb, const float* __restrict__ bb,
    const float* __restrict__ ip,
    const int* __restrict__ exit_idx, const int* __restrict__ raise_idx,
    float* __restrict__ wbuf, int useb)
{
  int tid = threadIdx.x;
  int wid = tid >> 6, lane = tid & 63;
  int gid = blockIdx.x*8 + wid;          // node id
  int b = gid >> 11, n = gid & 2047;

  float hv[8];
  if (useb){
    // dims lane*8 .. lane*8+7 of the interleaved 512-dim row
    uint4 raw = *(const uint4*)(sAll + (size_t)gid*512 + lane*8);
    hv[0] = b2f(raw.x & 0xffffu); hv[1] = b2f(raw.x >> 16);
    hv[2] = b2f(raw.y & 0xffffu); hv[3] = b2f(raw.y >> 16);
    hv[4] = b2f(raw.z & 0xffffu); hv[5] = b2f(raw.z >> 16);
    hv[6] = b2f(raw.w & 0xffffu); hv[7] = b2f(raw.w >> 16);
  } else {
    const float* bufs[4] = {c0, h0, c1, h1};
    const float* hb = bufs[lane >> 4] + (size_t)gid*128 + (lane & 15)*8;
    float4 hv0 = *(const float4*)hb;
    float4 hv1 = *(const float4*)(hb + 4);
    hv[0]=hv0.x; hv[1]=hv0.y; hv[2]=hv0.z; hv[3]=hv0.w;
    hv[4]=hv1.x; hv[5]=hv1.y; hv[6]=hv1.z; hv[7]=hv1.w;
  }
  const float* wrp = Wr + lane*16;       // dim = lane*8+j -> W[dim*2 + col]
  const float* wbp = Wb + lane*16;
  float r0=0.f, r1=0.f, q0=0.f, q1=0.f;
  #pragma unroll
  for (int j = 0; j < 8; j++){
    float h = hv[j];
    r0 += h * wrp[j*2];  r1 += h * wrp[j*2+1];
    q0 += h * wbp[j*2];  q1 += h * wbp[j*2+1];
  }
  #pragma unroll
  for (int off = 32; off > 0; off >>= 1){
    r0 += __shfl_xor(r0, off, 64);
    r1 += __shfl_xor(r1, off, 64);
    q0 += __shfl_xor(q0, off, 64);
    q1 += __shfl_xor(q1, off, 64);
  }
  if (lane == 0){
    r0 += br[0]; r1 += br[1];
    q0 += bb[0]; q1 += bb[1];
    float pr, pn;
    if (n == exit_idx[b] || n == raise_idx[b]){ pr = 0.f; pn = 1.f; }
    else {
      float m = fmaxf(r0, r1);
      float e0 = __expf(r0 - m), e1 = __expf(r1 - m);
      pr = e0 / (e0 + e1); pn = e1 / (e0 + e1);
    }
    float m2 = fmaxf(q0, q1);
    float f0 = __expf(q0 - m2), f1 = __expf(q1 - m2);
    float pt = f0 / (f0 + f1), pf = f1 / (f0 + f1);
    float ipv = ip[gid];
    wbuf[0*BN + gid] = pr * ipv;
    wbuf[1*BN + gid] = pn * pt * ipv;
    wbuf[2*BN + gid] = pn * pf * ipv;
  }
}

// ---------------- gather + normalize + output (4 nodes / block) -------------
__global__ __launch_bounds__(512) void kagg(
    const float* __restrict__ c0, const float* __restrict__ h0,
    const float* __restrict__ c1, const float* __restrict__ h1,
    const unsigned short* __restrict__ sAll,
    const float* __restrict__ ip,
    const float* __restrict__ wbuf, const unsigned short* __restrict__ edges,
    const int* __restrict__ counts, const int* __restrict__ offsets,
    const int* __restrict__ step_limits, const int* __restrict__ cur_step,
    float* __restrict__ out, int useb)
{
  int tid0 = threadIdx.x;
  int sub = tid0 >> 7;             // node within block (0..3)
  int tid = tid0 & 127;            // 0..127, channels tid*4..tid*4+3
  int gid = blockIdx.x*4 + sub;    // b*N + j
  int b = gid >> 11;
  size_t obase = (size_t)gid*513;
  const float* bufs[4] = {c0, h0, c1, h1};

  if (cur_step[0] >= step_limits[b]){       // done: copy old state + old ip
    int c = tid*4;
    const float* s = bufs[c >> 7];
    size_t rb = (size_t)gid*128 + (c & 127);
    __builtin_nontemporal_store(s[rb+0], &out[obase + c+0]);
    __builtin_nontemporal_store(s[rb+1], &out[obase + c+1]);
    __builtin_nontemporal_store(s[rb+2], &out[obase + c+2]);
    __builtin_nontemporal_store(s[rb+3], &out[obase + c+3]);
    if (tid == 0) __builtin_nontemporal_store(ip[gid], &out[obase + 512]);
    return;
  }

  int cnt = counts[gid], off = offsets[gid];
  const unsigned short* eb = edges + (size_t)b*3*NN + off;
  int lane = tid & 63;
  float a0=0.f, a1=0.f, a2=0.f, a3=0.f, ipn=0.f;

  if (useb){
    for (int base = 0; base < cnt; base += 64){
      int e = base + lane;
      int n_l = 0; float w_l = 0.f;
      if (e < cnt){
        int pk = eb[e];
        n_l = pk & 2047;
        w_l = wbuf[(pk >> 11)*BN + (b<<11) + n_l];
      }
      int m = min(cnt - base, 64);
      for (int j = 0; j < m; j++){
        int   n = __shfl(n_l, j, 64);
        float w = __shfl(w_l, j, 64);
        // dims tid*4..tid*4+3 of interleaved row (contiguous 1KB per node)
        uint2 raw = *(const uint2*)(sAll + ((size_t)(b<<11) + n)*512 + tid*4);
        ipn += w;
        a0 += w * b2f(raw.x & 0xffffu);
        a1 += w * b2f(raw.x >> 16);
        a2 += w * b2f(raw.y & 0xffffu);
        a3 += w * b2f(raw.y >> 16);
      }
    }
  } else {
    const float* sb = bufs[tid >> 5];
    int coff = (tid & 31)*4;
    for (int base = 0; base < cnt; base += 64){
      int e = base + lane;
      int n_l = 0; float w_l = 0.f;
      if (e < cnt){
        int pk = eb[e];
        n_l = pk & 2047;
        w_l = wbuf[(pk >> 11)*BN + (b<<11) + n_l];
      }
      int m = min(cnt - base, 64);
      for (int j = 0; j < m; j++){
        int   n = __shfl(n_l, j, 64);
        float w = __shfl(w_l, j, 64);
        float4 sv = *(const float4*)(sb + ((size_t)(b<<11) + n)*128 + coff);
        ipn += w;
        a0 += w * sv.x;
        a1 += w * sv.y;
        a2 += w * sv.z;
        a3 += w * sv.w;
      }
    }
  }
  int c = tid*4;
  float inv = 1.0f / (ipn + 1e-7f);
  __builtin_nontemporal_store(a0*inv, &out[obase + c+0]);
  __builtin_nontemporal_store(a1*inv, &out[obase + c+1]);
  __builtin_nontemporal_store(a2*inv, &out[obase + c+2]);
  __builtin_nontemporal_store(a3*inv, &out[obase + c+3]);
  if (tid == 0) __builtin_nontemporal_store(ipn, &out[obase + 512]);
}

extern "C" void kernel_launch(void* const* d_in, const int* in_sizes, int n_in,
                              void* d_out, int out_size, void* d_ws, size_t ws_size,
                              hipStream_t stream){
  const float* ne  = (const float*)d_in[0];
  float* c0  = (float*)d_in[1];   // updated in place only in f32-fallback mode
  float* h0  = (float*)d_in[2];
  float* c1  = (float*)d_in[3];
  float* h1  = (float*)d_in[4];
  const float* ip  = (const float*)d_in[5];
  const float* Wi0 = (const float*)d_in[6];
  const float* Wh0 = (const float*)d_in[7];
  const float* b0  = (const float*)d_in[8];
  const float* Wi1 = (const float*)d_in[9];
  const float* Wh1 = (const float*)d_in[10];
  const float* b1  = (const float*)d_in[11];
  const float* Wr  = (const float*)d_in[12];
  const float* br  = (const float*)d_in[13];
  const float* Wb  = (const float*)d_in[14];
  const float* bb  = (const float*)d_in[15];
  const int* ti  = (const int*)d_in[16];
  const int* fi  = (const int*)d_in[17];
  const int* ri  = (const int*)d_in[18];
  const int* ei  = (const int*)d_in[19];
  const int* rni = (const int*)d_in[20];
  const int* sl  = (const int*)d_in[21];
  const int* cs  = (const int*)d_in[22];
  float* out = (float*)d_out;

  // --- ws layout ---
  uint8_t* ws = (uint8_t*)d_ws;
  unsigned short* Bsw0    = (unsigned short*)(ws + 0);         // 262144 B
  unsigned short* Bsw1    = (unsigned short*)(ws + 262144);    // 262144 B
  float*          wbuf    = (float*)(ws + 655360);             // 786432 B
  int*            counts  = (int*)(ws + 1441792);              // 262144 B
  int*            offsets = (int*)(ws + 1703936);              // 262144 B
  unsigned short* edges   = (unsigned short*)(ws + 2228224);   // 393216 B
  // interleaved bf16 state sink (masked contrib), 64 MiB
  const size_t SBASE = 2621440;                                // 16B aligned
  const size_t SB    = (size_t)BN * 512 * 2;                   // 64 MiB
  int useb = (ws_size >= SBASE + SB) ? 1 : 0;
  unsigned short* sAll = (unsigned short*)(ws + SBASE);

  // B pre-swizzle (must precede klstm2)
  kswz<<<64, 512, 0, stream>>>(Wi0, Wh0, Wi1, Wh1, Bsw0, Bsw1);

  // fused 2-layer LSTM (blocks 32..2079) + CSR build (blocks 0..31, hidden)
  klstm2<<<32 + BN/ROWSB, 512, 0, stream>>>(ne, c0, h0, c1, h1, sAll,
                                            Bsw0, b0, Bsw1, b1,
                                            ei, rni, ri, ti, fi,
                                            counts, offsets, edges,
                                            sl, cs, useb);

  // decisions
  kdec<<<BN/8, 512, 0, stream>>>(c0, h0, c1, h1, sAll,
                                 Wr, br, Wb, bb, ip, ei, rni, wbuf, useb);

  kagg<<<BN/4, 512, 0, stream>>>(c0, h0, c1, h1, sAll,
                                 ip, wbuf, edges, counts, offsets,
                                 sl, cs, out, useb);
}